// Round 3
// baseline (7799.213 us; speedup 1.0000x reference)
//
#include <hip/hip_runtime.h>
#include <math.h>

#define BB   16
#define TFULL 4096
#define T2   2048
#define LSEQ 2019
#define HSTR 2048
#define CIN  64
#define CO   32
#define HD   64
#define NST  64
#define NLAY 8
#define DOUT 640
#define EPSF 1e-5f
#define NCH  32
#define CHL  64
#define EROW 66   // padded row stride (entries, 16B each) for E-table

static __device__ __forceinline__ float sigm(float x){ return 1.f/(1.f + __expf(-x)); }
static __device__ __forceinline__ float gelu_(float x){ return 0.5f*x*(1.f + erff(x*0.7071067811865475f)); }

// ---------------- Stage A: pw1 conv + GN1 partial stats ----------------
__global__ void __launch_bounds__(256) k_pw1(const float* __restrict__ x,
                                             const float* __restrict__ w,
                                             const float* __restrict__ bias,
                                             float* __restrict__ u1,
                                             float* __restrict__ stats){
  int blk = blockIdx.x;
  int b  = blk >> 6;
  int t0 = (blk & 63) << 6;
  __shared__ float xs[CIN][64];
  __shared__ float wsm[CO*CIN];
  __shared__ float red[8];
  int tid = threadIdx.x;
  for (int i = tid; i < CIN*64; i += 256){
    int c = i >> 6, t = i & 63;
    xs[c][t] = x[((long)(b*CIN + c))*TFULL + t0 + t];
  }
  for (int i = tid; i < CO*CIN; i += 256) wsm[i] = w[i];
  __syncthreads();
  int t  = tid & 63;
  int o0 = tid >> 6;
  float lsum = 0.f, lsq = 0.f;
  for (int o = o0; o < CO; o += 4){
    float acc = bias[o];
    #pragma unroll
    for (int c = 0; c < CIN; ++c) acc = fmaf(wsm[o*CIN + c], xs[c][t], acc);
    u1[((long)(b*CO + o))*TFULL + t0 + t] = acc;
    lsum += acc; lsq += acc*acc;
  }
  #pragma unroll
  for (int off = 32; off; off >>= 1){ lsum += __shfl_down(lsum, off); lsq += __shfl_down(lsq, off); }
  if ((tid & 63) == 0){ red[tid>>6] = lsum; red[4 + (tid>>6)] = lsq; }
  __syncthreads();
  if (tid == 0){
    atomicAdd(&stats[b],      red[0]+red[1]+red[2]+red[3]);
    atomicAdd(&stats[16 + b], red[4]+red[5]+red[6]+red[7]);
  }
}

__global__ void k_gnstat(float* __restrict__ stats, int which, float cnt){
  int b = threadIdx.x;
  if (b < BB){
    int o = which * 64;
    float m = stats[o + b] / cnt;
    float v = stats[o + 16 + b] / cnt - m*m;
    stats[o + 32 + b] = m;
    stats[o + 48 + b] = rsqrtf(v + EPSF);
  }
}

// ---------------- Stage A3: GN1 apply + GLU(time) + SiLU ----------------
__global__ void __launch_bounds__(256) k_glu_silu(const float* __restrict__ u1,
                                                  const float* __restrict__ g,
                                                  const float* __restrict__ bb,
                                                  const float* __restrict__ stats,
                                                  float* __restrict__ u2){
  int blk = blockIdx.x;
  int b  = blk >> 5;
  int t0 = (blk & 31) << 6;
  float m = stats[32 + b], r = stats[48 + b];
  int tid = threadIdx.x;
  int t = t0 + (tid & 63);
  for (int c = tid >> 6; c < CO; c += 4){
    long base = ((long)(b*CO + c))*TFULL;
    float a  = u1[base + t];
    float bv = u1[base + t + T2];
    float gc = g[c], bc = bb[c];
    a  = (a  - m)*r*gc + bc;
    bv = (bv - m)*r*gc + bc;
    float z = a * sigm(bv);
    z = z * sigm(z);
    u2[((long)(b*CO + c))*T2 + t] = z;
  }
}

// ---------------- Stage B1: depthwise conv (K=32, pad 1) + GN2 partial stats ----------------
__global__ void __launch_bounds__(256) k_dconv(const float* __restrict__ u2,
                                               const float* __restrict__ w,
                                               const float* __restrict__ bias,
                                               float* __restrict__ v,
                                               float* __restrict__ stats){
  int blk = blockIdx.x;
  int b = blk >> 5, c = blk & 31;
  __shared__ float row[T2 + 2];
  __shared__ float red[8];
  int tid = threadIdx.x;
  if (tid == 0){ row[0] = 0.f; row[T2 + 1] = 0.f; }
  const float* src = u2 + ((long)(b*CO + c))*T2;
  for (int i = tid; i < T2; i += 256) row[1 + i] = src[i];
  __syncthreads();
  float wk[32];
  #pragma unroll
  for (int k = 0; k < 32; ++k) wk[k] = w[c*32 + k];
  float bc = bias[c];
  float lsum = 0.f, lsq = 0.f;
  float* dst = v + ((long)(b*CO + c))*LSEQ;
  for (int t = tid; t < LSEQ; t += 256){
    float acc = bc;
    #pragma unroll
    for (int k = 0; k < 32; ++k) acc = fmaf(wk[k], row[t + k], acc);
    dst[t] = acc;
    lsum += acc; lsq += acc*acc;
  }
  #pragma unroll
  for (int off = 32; off; off >>= 1){ lsum += __shfl_down(lsum, off); lsq += __shfl_down(lsq, off); }
  if ((tid & 63) == 0){ red[tid>>6] = lsum; red[4 + (tid>>6)] = lsq; }
  __syncthreads();
  if (tid == 0){
    atomicAdd(&stats[64 + b], red[0]+red[1]+red[2]+red[3]);
    atomicAdd(&stats[80 + b], red[4]+red[5]+red[6]+red[7]);
  }
}

// ---------------- Stage B3: GN2 apply + pw2 + encoder -> h (B,HD,HSTR) ----------------
__global__ void __launch_bounds__(256) k_pw2enc(const float* __restrict__ v,
                                                const float* __restrict__ g2,
                                                const float* __restrict__ b2,
                                                const float* __restrict__ pw2w,
                                                const float* __restrict__ pw2b,
                                                const float* __restrict__ encw,
                                                const float* __restrict__ encb,
                                                const float* __restrict__ stats,
                                                float* __restrict__ h){
  int blk = blockIdx.x;
  int b  = blk >> 5;
  int t0 = (blk & 31) << 6;
  int tcnt = min(64, LSEQ - t0);
  __shared__ float vn[CO][64];
  __shared__ float p2[CO*CO];
  __shared__ float ew[CO*HD];
  __shared__ float u3[4][CO];
  __shared__ float hout[HD][65];
  int tid = threadIdx.x;
  float m = stats[96 + b], r = stats[112 + b];
  for (int i = tid; i < CO*CO; i += 256){
    int o = i & 31, c = i >> 5;
    p2[c*CO + o] = pw2w[o*CO + c];
  }
  for (int i = tid; i < CO*HD; i += 256) ew[i] = encw[i];
  for (int i = tid; i < CO*64; i += 256){
    int c = i >> 6, t = i & 63;
    float val = 0.f;
    if (t < tcnt) val = v[((long)(b*CO + c))*LSEQ + t0 + t];
    vn[c][t] = (val - m)*r*g2[c] + b2[c];
  }
  __syncthreads();
  int wv = tid >> 6, ln = tid & 63;
  for (int i = 0; i < 16; ++i){
    int tt = wv*16 + i;
    if (ln < CO){
      float acc = pw2b[ln];
      #pragma unroll
      for (int c = 0; c < CO; ++c) acc = fmaf(p2[c*CO + ln], vn[c][tt], acc);
      u3[wv][ln] = acc;
    }
    float hacc = encb[ln];
    #pragma unroll
    for (int c = 0; c < CO; ++c) hacc = fmaf(ew[c*HD + ln], u3[wv][c], hacc);
    hout[ln][tt] = hacc;
  }
  __syncthreads();
  for (int i = tid; i < HD*64; i += 256){
    int d = i >> 6, t = i & 63;
    if (t < tcnt) h[((long)(b*HD + d))*HSTR + t0 + t] = hout[d][t];
  }
}

// ---------------- S4D coefficients + K taps for ALL layers ----------------
// ktap[l][h][k] = 2 Re sum_n cd_n w_n^k  (k=0..63) — batch-independent, computed once.
__global__ void k_coef(const float* __restrict__ log_dt, const float* __restrict__ logA,
                       const float* __restrict__ Aim, const float* __restrict__ Cre,
                       const float* __restrict__ Cim, float* __restrict__ coef,
                       float* __restrict__ ktap){
  int blk = blockIdx.x;
  int l = blk >> 6, hh = blk & 63;
  int n = threadIdx.x;
  __shared__ float tk[64][65];
  float dt = expf(log_dt[l*HD + hh]);
  int idx = (l*HD + hh)*NST + n;
  float Ar = -expf(logA[idx]);
  float Ai = Aim[idx];
  float dr = Ar*dt, di = Ai*dt;
  float er = expf(dr);
  float wr = er*cosf(di), wi = er*sinf(di);
  float inv = 1.f/(Ar*Ar + Ai*Ai);
  float xr = wr - 1.f, xi = wi;
  float qr = (xr*Ar + xi*Ai)*inv;
  float qi = (xi*Ar - xr*Ai)*inv;
  float cr = Cre[idx], ci = Cim[idx];
  float cdr = cr*qr - ci*qi;
  float cdi = cr*qi + ci*qr;
  float* cl = coef + l*4*HD*NST;
  int hn = hh*NST + n;
  cl[hn]            = wr;
  cl[HD*NST + hn]   = wi;
  cl[2*HD*NST + hn] = cdr;
  cl[3*HD*NST + hn] = cdi;
  {
    float pr = cdr, pi = cdi;   // cd * w^0
    for (int k = 0; k < 64; ++k){
      tk[n][k] = pr;
      float t2 = pr*wr - pi*wi; pi = pr*wi + pi*wr; pr = t2;
    }
  }
  __syncthreads();
  {
    float s = 0.f;
    for (int m = 0; m < 64; ++m) s += tk[m][n];
    ktap[(l*HD + hh)*64 + n] = 2.f*s;
  }
}

// ---------------- S4D chunk-parallel scan ----------------
// v4: 512 threads (8 waves) per (b,h) tile. Per-thread state halved by construction:
//  - wave owns 4 chunks (phase-1 vr/vi[4]); thread produces 4 outputs (acc[4]).
//  - FULL E-table (32 rows) built ONCE — no mid-kernel rebuild holding accs live
//    (the round-1/2 spill trap: np-outer + rebuild pushed pressure past 256).
//  - ktap precomputed; S reads broadcast; e reads lane-consecutive b128.
// LDS 59,904 B -> 2 blocks/CU = 16 waves/CU = 4 waves/SIMD at VGPR<=128.
__global__ void __launch_bounds__(512, 4) k_s4d(const float* __restrict__ h,
                                                const float* __restrict__ coef,
                                                const float* __restrict__ ktap,
                                                int layer, float* __restrict__ y){
  int blk = blockIdx.x;
  int b = blk >> 6, hh = blk & 63;
  __shared__ float u_s[2048];
  __shared__ float Eh[32*EROW*4];
  __shared__ float S_s[NCH*128];
  __shared__ float Kpad[128];
  __shared__ float wc[256];        // wr[64] | wi[64] | cdr[64] | cdi[64]
  int tid = threadIdx.x;
  int n = tid & 63, q = tid >> 6;  // lane, wave (0..7)
  const float* cl = coef + layer*4*HD*NST;
  int hn = hh*NST + n;
  float wr  = cl[hn];
  float wi  = cl[HD*NST + hn];
  const float* up = h + ((long)(b*HD + hh))*HSTR;

  // u load: 512 threads x 4 floats
  {
    int base = tid*4;
    if (base + 4 <= LSEQ){
      *(float4*)&u_s[base] = *(const float4*)(up + base);
    } else {
      #pragma unroll
      for (int k = 0; k < 4; ++k){
        int t = base + k;
        u_s[t] = (t < LSEQ) ? up[t] : 0.f;
      }
    }
  }
  if (q == 0){
    wc[n]       = wr;
    wc[64 + n]  = wi;
    wc[128 + n] = cl[2*HD*NST + hn];
    wc[192 + n] = cl[3*HD*NST + hn];
  }
  if (tid < 64) Kpad[tid] = 0.f;
  else if (tid < 128) Kpad[tid] = ktap[(layer*HD + hh)*64 + (tid - 64)];
  __syncthreads();

  // build FULL E-table: Eh[np][k-1] = float4(2cd_{2np}w^k, 2cd_{2np+1}w^k), k=1..64.
  // 512 threads: np=tid>>4 (0..31), par=(tid&1), seg=(tid&15)>>1 -> k in [seg*8+1, seg*8+8]
  {
    int np = tid >> 4, rr = tid & 15;
    int par = rr & 1, seg = rr >> 1;
    int s = np*2 + par;
    float ws = wc[s], wis = wc[64 + s], crs = wc[128 + s], cis = wc[192 + s];
    float ar = ws, ai = wis;
    #pragma unroll
    for (int t2i = 0; t2i < 3; ++t2i){ float t2 = ar*ar - ai*ai; ai = 2.f*ar*ai; ar = t2; }  // w^8
    float pr = 1.f, pi = 0.f;
    for (int k = 0; k < seg; ++k){ float t2 = pr*ar - pi*ai; pi = pr*ai + pi*ar; pr = t2; }   // w^(8seg)
    { float t2 = pr*ws - pi*wis; pi = pr*wis + pi*ws; pr = t2; }                              // w^(8seg+1)
    float* bp = &Eh[(np*EROW + seg*8)*4 + par*2];
    for (int k = 0; k < 8; ++k){
      float2 ev;
      ev.x = 2.f*(crs*pr - cis*pi);
      ev.y = 2.f*(crs*pi + cis*pr);
      *(float2*)bp = ev;
      float t2 = pr*ws - pi*wis; pi = pr*wis + pi*ws; pr = t2;
      bp += 4;
    }
  }

  // phase 1: per-chunk decayed input sums; wave q owns chunks q*4..q*4+3 (float4 Horner)
  int cbase = q*4;
  {
    float vr[4], vi[4];
    #pragma unroll
    for (int c = 0; c < 4; ++c){ vr[c] = 0.f; vi[c] = 0.f; }
    for (int j4 = 0; j4 < 64; j4 += 4){
      #pragma unroll
      for (int c = 0; c < 4; ++c){
        float4 uu = *(const float4*)&u_s[(cbase + c)*64 + j4];
        float xr = vr[c], xi = vi[c];
        float a_r = fmaf(wr, xr,  fmaf(-wi, xi,  uu.x));
        float a_i = fmaf(wr, xi,  wi*xr);
        float b_r = fmaf(wr, a_r, fmaf(-wi, a_i, uu.y));
        float b_i = fmaf(wr, a_i, wi*a_r);
        float c_r = fmaf(wr, b_r, fmaf(-wi, b_i, uu.z));
        float c_i = fmaf(wr, b_i, wi*b_r);
        vr[c] = fmaf(wr, c_r, fmaf(-wi, c_i, uu.w));
        vi[c] = fmaf(wr, c_i, wi*c_r);
      }
    }
    #pragma unroll
    for (int c = 0; c < 4; ++c){
      float2 sv = {vr[c], vi[c]};
      *(float2*)&S_s[(cbase + c)*128 + 2*n] = sv;
    }
  }
  __syncthreads();

  // phase 2 (wave 0): chunk-state exclusive scan (in place)
  if (q == 0){
    float ar = wr, ai = wi;
    #pragma unroll
    for (int s = 0; s < 6; ++s){ float t2 = ar*ar - ai*ai; ai = 2.f*ar*ai; ar = t2; }  // w^64
    float sr = 0.f, si = 0.f;
    for (int c = 0; c < NCH; ++c){
      float vr2 = S_s[c*128 + 2*n], vi2 = S_s[c*128 + 2*n + 1];
      float2 sv = {sr, si};
      *(float2*)&S_s[c*128 + 2*n] = sv;
      float nr = fmaf(ar, sr, fmaf(-ai, si, vr2));
      float ni = fmaf(ar, si, fmaf(ai, sr, vi2));
      sr = nr; si = ni;
    }
  }
  __syncthreads();

  // phase 3: state contributions (np-outer; 1 lane-varying e-read feeds 4 broadcast S-reads)
  float acc[4];
  #pragma unroll
  for (int c = 0; c < 4; ++c) acc[c] = 0.f;
  for (int np = 0; np < 32; ++np){
    float4 e = *(const float4*)&Eh[(np*EROW + n)*4];
    #pragma unroll
    for (int c = 0; c < 4; ++c){
      float4 s = *(const float4*)&S_s[(cbase + c)*128 + np*4];
      acc[c] = fmaf(e.x,s.x, fmaf(-e.y,s.y, fmaf(e.z,s.z, fmaf(-e.w,s.w, acc[c]))));
    }
  }

  // in-chunk convolution (taps shared across the thread's 4 chunk-outputs) + store
  const float* Kb = &Kpad[64 + n];
  for (int j4 = 0; j4 < 64; j4 += 4){
    float k0 = Kb[-j4], k1 = Kb[-j4-1], k2 = Kb[-j4-2], k3 = Kb[-j4-3];
    #pragma unroll
    for (int c = 0; c < 4; ++c){
      float4 u4 = *(const float4*)&u_s[(cbase + c)*64 + j4];
      acc[c] = fmaf(k0,u4.x, fmaf(k1,u4.y, fmaf(k2,u4.z, fmaf(k3,u4.w, acc[c]))));
    }
  }
  float* yo = y + ((long)(b*HD + hh))*HSTR;
  #pragma unroll
  for (int c = 0; c < 4; ++c){
    int t = (cbase + c)*64 + n;
    if (t < LSEQ) yo[t] = acc[c];
  }
}

// ---------------- S4D post: register-tiled GEMM + GLU + residual + LN ----------------
__global__ void __launch_bounds__(256) k_post(const float* __restrict__ y,
                                              float* __restrict__ h,
                                              const float* __restrict__ D,
                                              const float* __restrict__ ow,
                                              const float* __restrict__ ob,
                                              const float* __restrict__ lng,
                                              const float* __restrict__ lnb,
                                              int layer){
  int blk = blockIdx.x;
  int b  = blk >> 5;
  int t0 = (blk & 31) << 6;
  __shared__ float Ws[64*128];     // [c][o]
  __shared__ float Ys[64*68];      // [c][t]; reused as z-buffer
  __shared__ float mstat[64], rstat[64];
  int tid = threadIdx.x;
  const float* owp = ow + layer*2*HD*HD;
  const float* obp = ob + layer*2*HD;
  {
    int o = tid >> 1, cs = (tid & 1)*32;
    const float* wrow = owp + o*HD + cs;
    #pragma unroll
    for (int k = 0; k < 8; ++k){
      float4 w4 = *(const float4*)(wrow + k*4);
      Ws[(cs + k*4 + 0)*128 + o] = w4.x;
      Ws[(cs + k*4 + 1)*128 + o] = w4.y;
      Ws[(cs + k*4 + 2)*128 + o] = w4.z;
      Ws[(cs + k*4 + 3)*128 + o] = w4.w;
    }
  }
  {
    int c = tid >> 2, qq = tid & 3;
    float dl = D[layer*HD + c];
    const float* yrow = y + ((long)(b*HD + c))*HSTR + t0 + qq*16;
    const float* hrow = h + ((long)(b*HD + c))*HSTR + t0 + qq*16;
    #pragma unroll
    for (int k = 0; k < 4; ++k){
      float4 yv = *(const float4*)(yrow + k*4);
      float4 hv = *(const float4*)(hrow + k*4);
      float4 g4;
      g4.x = gelu_(fmaf(hv.x, dl, yv.x));
      g4.y = gelu_(fmaf(hv.y, dl, yv.y));
      g4.z = gelu_(fmaf(hv.z, dl, yv.z));
      g4.w = gelu_(fmaf(hv.w, dl, yv.w));
      *(float4*)&Ys[c*68 + qq*16 + k*4] = g4;
    }
  }
  __syncthreads();
  int og = tid >> 4, tg = tid & 15;
  int o0 = og*4, tt0 = tg*4;
  float accA[4][4], accG[4][4];
  #pragma unroll
  for (int i = 0; i < 4; ++i){
    float ba = obp[o0 + i], bg = obp[64 + o0 + i];
    #pragma unroll
    for (int j = 0; j < 4; ++j){ accA[i][j] = ba; accG[i][j] = bg; }
  }
  for (int c = 0; c < 64; ++c){
    float4 wa = *(const float4*)&Ws[c*128 + o0];
    float4 wg = *(const float4*)&Ws[c*128 + 64 + o0];
    float4 yv = *(const float4*)&Ys[c*68 + tt0];
    float yvv[4] = {yv.x, yv.y, yv.z, yv.w};
    float wav[4] = {wa.x, wa.y, wa.z, wa.w};
    float wgv[4] = {wg.x, wg.y, wg.z, wg.w};
    #pragma unroll
    for (int i = 0; i < 4; ++i){
      #pragma unroll
      for (int j = 0; j < 4; ++j){
        accA[i][j] = fmaf(wav[i], yvv[j], accA[i][j]);
        accG[i][j] = fmaf(wgv[i], yvv[j], accG[i][j]);
      }
    }
  }
  __syncthreads();
  float r[4][4];
  #pragma unroll
  for (int i = 0; i < 4; ++i){
    int c = o0 + i;
    const float* hrow = h + ((long)(b*HD + c))*HSTR + t0 + tt0;
    #pragma unroll
    for (int j = 0; j < 4; ++j){
      int t = t0 + tt0 + j;
      float hold = (t < LSEQ) ? hrow[j] : 0.f;
      float z = accA[i][j] * sigm(accG[i][j]);
      r[i][j] = z + hold;
    }
    float4 rr = {r[i][0], r[i][1], r[i][2], r[i][3]};
    *(float4*)&Ys[c*68 + tt0] = rr;
  }
  __syncthreads();
  if (tid < 64){
    float s1 = 0.f, s2 = 0.f;
    for (int c = 0; c < 64; ++c){
      float v = Ys[c*68 + tid];
      s1 += v; s2 += v*v;
    }
    float m = s1 * (1.f/64.f);
    float var = fmaf(-m, m, s2 * (1.f/64.f));
    mstat[tid] = m;
    rstat[tid] = rsqrtf(var + EPSF);
  }
  __syncthreads();
  #pragma unroll
  for (int i = 0; i < 4; ++i){
    int c = o0 + i;
    float gl = lng[layer*HD + c], bl = lnb[layer*HD + c];
    float* hrow = h + ((long)(b*HD + c))*HSTR + t0 + tt0;
    if (t0 + tt0 + 3 < LSEQ){
      float4 o4v;
      o4v.x = fmaf((r[i][0] - mstat[tt0+0])*rstat[tt0+0], gl, bl);
      o4v.y = fmaf((r[i][1] - mstat[tt0+1])*rstat[tt0+1], gl, bl);
      o4v.z = fmaf((r[i][2] - mstat[tt0+2])*rstat[tt0+2], gl, bl);
      o4v.w = fmaf((r[i][3] - mstat[tt0+3])*rstat[tt0+3], gl, bl);
      *(float4*)hrow = o4v;
    } else {
      #pragma unroll
      for (int j = 0; j < 4; ++j){
        int t = t0 + tt0 + j;
        if (t < LSEQ) hrow[j] = fmaf((r[i][j] - mstat[tt0+j])*rstat[tt0+j], gl, bl);
      }
    }
  }
}

// ---------------- Decoder: register-blocked, weight-reuse GEMM ----------------
__global__ void __launch_bounds__(320) k_dec(const float* __restrict__ h,
                                             const float* __restrict__ w,
                                             const float* __restrict__ bias,
                                             float* __restrict__ out){
  int blk = blockIdx.x;
  int b  = blk >> 6;
  int t0 = (blk & 63) << 5;
  __shared__ float hl[HD][32];
  int tid = threadIdx.x;
  for (int i = tid; i < HD*32; i += 320){
    int d = i >> 5, t = i & 31;
    int tt = t0 + t;
    hl[d][t] = (tt < LSEQ) ? h[((long)(b*HD + d))*HSTR + tt] : 0.f;
  }
  __syncthreads();
  int o4 = tid % 160, th = tid / 160;
  int tb = th * 16;
  float4 acc[16];
  const float4 b4 = *(const float4*)(bias + o4*4);
  #pragma unroll
  for (int i = 0; i < 16; ++i) acc[i] = b4;
  const float* wp = w + o4*4;
  for (int d = 0; d < HD; ++d){
    float4 w4 = *(const float4*)(wp + (long)d*DOUT);
    #pragma unroll
    for (int ii = 0; ii < 4; ++ii){
      float4 h4 = *(const float4*)&hl[d][tb + ii*4];
      float hvv[4] = {h4.x, h4.y, h4.z, h4.w};
      #pragma unroll
      for (int jj = 0; jj < 4; ++jj){
        int i = ii*4 + jj;
        acc[i].x = fmaf(hvv[jj], w4.x, acc[i].x);
        acc[i].y = fmaf(hvv[jj], w4.y, acc[i].y);
        acc[i].z = fmaf(hvv[jj], w4.z, acc[i].z);
        acc[i].w = fmaf(hvv[jj], w4.w, acc[i].w);
      }
    }
  }
  #pragma unroll
  for (int i = 0; i < 16; ++i){
    int t = t0 + tb + i;
    if (t < LSEQ) *(float4*)(out + ((long)(b*LSEQ) + t)*DOUT + o4*4) = acc[i];
  }
}

extern "C" void kernel_launch(void* const* d_in, const int* in_sizes, int n_in,
                              void* d_out, int out_size, void* d_ws, size_t ws_size,
                              hipStream_t stream){
  const float* x     = (const float*)d_in[0];
  const float* pw1_w = (const float*)d_in[1];
  const float* pw1_b = (const float*)d_in[2];
  const float* gn1_g = (const float*)d_in[3];
  const float* gn1_b = (const float*)d_in[4];
  const float* dw_w  = (const float*)d_in[5];
  const float* dw_b  = (const float*)d_in[6];
  const float* gn2_g = (const float*)d_in[7];
  const float* gn2_b = (const float*)d_in[8];
  const float* pw2_w = (const float*)d_in[9];
  const float* pw2_b = (const float*)d_in[10];
  const float* enc_w = (const float*)d_in[11];
  const float* enc_b = (const float*)d_in[12];
  const float* log_dt= (const float*)d_in[13];
  const float* logA  = (const float*)d_in[14];
  const float* Aim   = (const float*)d_in[15];
  const float* Cre   = (const float*)d_in[16];
  const float* Cim   = (const float*)d_in[17];
  const float* Dp    = (const float*)d_in[18];
  const float* owp   = (const float*)d_in[19];
  const float* obp   = (const float*)d_in[20];
  const float* lng   = (const float*)d_in[21];
  const float* lnb   = (const float*)d_in[22];
  const float* dec_w = (const float*)d_in[23];
  const float* dec_b = (const float*)d_in[24];
  float* out = (float*)d_out;

  float* ws   = (float*)d_ws;
  float* u1   = ws;
  float* u2   = u1 + 2097152;
  float* vv   = u2 + 1048576;
  float* hbuf = vv + 1033728;
  float* coef = hbuf + 2097152;
  float* stats= coef + 131072;
  float* ktap = stats + 128;       // NLAY*HD*64 = 32768 floats
  float* ybuf = u1;

  hipMemsetAsync(stats, 0, 128*sizeof(float), stream);
  k_coef<<<NLAY*HD, 64, 0, stream>>>(log_dt, logA, Aim, Cre, Cim, coef, ktap);
  k_pw1<<<BB*64, 256, 0, stream>>>(x, pw1_w, pw1_b, u1, stats);
  k_gnstat<<<1, 64, 0, stream>>>(stats, 0, (float)(CO*TFULL));
  k_glu_silu<<<BB*32, 256, 0, stream>>>(u1, gn1_g, gn1_b, stats, u2);
  k_dconv<<<BB*CO, 256, 0, stream>>>(u2, dw_w, dw_b, vv, stats);
  k_gnstat<<<1, 64, 0, stream>>>(stats, 1, (float)(CO*LSEQ));
  k_pw2enc<<<BB*32, 256, 0, stream>>>(vv, gn2_g, gn2_b, pw2_w, pw2_b, enc_w, enc_b, stats, hbuf);
  for (int l = 0; l < NLAY; ++l){
    k_s4d<<<BB*HD, 512, 0, stream>>>(hbuf, coef, ktap, l, ybuf);
    k_post<<<BB*32, 256, 0, stream>>>(ybuf, hbuf, Dp, owp, obp, lng, lnb, l);
  }
  k_dec<<<BB*64, 320, 0, stream>>>(hbuf, dec_w, dec_b, out);
}

// Round 4
// 5964.256 us; speedup vs baseline: 1.3077x; 1.3077x over previous
//
#include <hip/hip_runtime.h>
#include <math.h>

#define BB   16
#define TFULL 4096
#define T2   2048
#define LSEQ 2019
#define HSTR 2048
#define CIN  64
#define CO   32
#define HD   64
#define NST  64
#define NLAY 8
#define DOUT 640
#define EPSF 1e-5f
#define NCH  32
#define CHL  64
#define EROW 66   // padded row stride (entries, 16B each) for E-table

static __device__ __forceinline__ float sigm(float x){ return 1.f/(1.f + __expf(-x)); }
static __device__ __forceinline__ float gelu_(float x){ return 0.5f*x*(1.f + erff(x*0.7071067811865475f)); }

// ---------------- Stage A: pw1 conv + GN1 partial stats ----------------
__global__ void __launch_bounds__(256) k_pw1(const float* __restrict__ x,
                                             const float* __restrict__ w,
                                             const float* __restrict__ bias,
                                             float* __restrict__ u1,
                                             float* __restrict__ stats){
  int blk = blockIdx.x;
  int b  = blk >> 6;
  int t0 = (blk & 63) << 6;
  __shared__ float xs[CIN][64];
  __shared__ float wsm[CO*CIN];
  __shared__ float red[8];
  int tid = threadIdx.x;
  for (int i = tid; i < CIN*64; i += 256){
    int c = i >> 6, t = i & 63;
    xs[c][t] = x[((long)(b*CIN + c))*TFULL + t0 + t];
  }
  for (int i = tid; i < CO*CIN; i += 256) wsm[i] = w[i];
  __syncthreads();
  int t  = tid & 63;
  int o0 = tid >> 6;
  float lsum = 0.f, lsq = 0.f;
  for (int o = o0; o < CO; o += 4){
    float acc = bias[o];
    #pragma unroll
    for (int c = 0; c < CIN; ++c) acc = fmaf(wsm[o*CIN + c], xs[c][t], acc);
    u1[((long)(b*CO + o))*TFULL + t0 + t] = acc;
    lsum += acc; lsq += acc*acc;
  }
  #pragma unroll
  for (int off = 32; off; off >>= 1){ lsum += __shfl_down(lsum, off); lsq += __shfl_down(lsq, off); }
  if ((tid & 63) == 0){ red[tid>>6] = lsum; red[4 + (tid>>6)] = lsq; }
  __syncthreads();
  if (tid == 0){
    atomicAdd(&stats[b],      red[0]+red[1]+red[2]+red[3]);
    atomicAdd(&stats[16 + b], red[4]+red[5]+red[6]+red[7]);
  }
}

__global__ void k_gnstat(float* __restrict__ stats, int which, float cnt){
  int b = threadIdx.x;
  if (b < BB){
    int o = which * 64;
    float m = stats[o + b] / cnt;
    float v = stats[o + 16 + b] / cnt - m*m;
    stats[o + 32 + b] = m;
    stats[o + 48 + b] = rsqrtf(v + EPSF);
  }
}

// ---------------- Stage A3: GN1 apply + GLU(time) + SiLU ----------------
__global__ void __launch_bounds__(256) k_glu_silu(const float* __restrict__ u1,
                                                  const float* __restrict__ g,
                                                  const float* __restrict__ bb,
                                                  const float* __restrict__ stats,
                                                  float* __restrict__ u2){
  int blk = blockIdx.x;
  int b  = blk >> 5;
  int t0 = (blk & 31) << 6;
  float m = stats[32 + b], r = stats[48 + b];
  int tid = threadIdx.x;
  int t = t0 + (tid & 63);
  for (int c = tid >> 6; c < CO; c += 4){
    long base = ((long)(b*CO + c))*TFULL;
    float a  = u1[base + t];
    float bv = u1[base + t + T2];
    float gc = g[c], bc = bb[c];
    a  = (a  - m)*r*gc + bc;
    bv = (bv - m)*r*gc + bc;
    float z = a * sigm(bv);
    z = z * sigm(z);
    u2[((long)(b*CO + c))*T2 + t] = z;
  }
}

// ---------------- Stage B1: depthwise conv (K=32, pad 1) + GN2 partial stats ----------------
__global__ void __launch_bounds__(256) k_dconv(const float* __restrict__ u2,
                                               const float* __restrict__ w,
                                               const float* __restrict__ bias,
                                               float* __restrict__ v,
                                               float* __restrict__ stats){
  int blk = blockIdx.x;
  int b = blk >> 5, c = blk & 31;
  __shared__ float row[T2 + 2];
  __shared__ float red[8];
  int tid = threadIdx.x;
  if (tid == 0){ row[0] = 0.f; row[T2 + 1] = 0.f; }
  const float* src = u2 + ((long)(b*CO + c))*T2;
  for (int i = tid; i < T2; i += 256) row[1 + i] = src[i];
  __syncthreads();
  float wk[32];
  #pragma unroll
  for (int k = 0; k < 32; ++k) wk[k] = w[c*32 + k];
  float bc = bias[c];
  float lsum = 0.f, lsq = 0.f;
  float* dst = v + ((long)(b*CO + c))*LSEQ;
  for (int t = tid; t < LSEQ; t += 256){
    float acc = bc;
    #pragma unroll
    for (int k = 0; k < 32; ++k) acc = fmaf(wk[k], row[t + k], acc);
    dst[t] = acc;
    lsum += acc; lsq += acc*acc;
  }
  #pragma unroll
  for (int off = 32; off; off >>= 1){ lsum += __shfl_down(lsum, off); lsq += __shfl_down(lsq, off); }
  if ((tid & 63) == 0){ red[tid>>6] = lsum; red[4 + (tid>>6)] = lsq; }
  __syncthreads();
  if (tid == 0){
    atomicAdd(&stats[64 + b], red[0]+red[1]+red[2]+red[3]);
    atomicAdd(&stats[80 + b], red[4]+red[5]+red[6]+red[7]);
  }
}

// ---------------- Stage B3: GN2 apply + pw2 + encoder -> h (B,HD,HSTR) ----------------
__global__ void __launch_bounds__(256) k_pw2enc(const float* __restrict__ v,
                                                const float* __restrict__ g2,
                                                const float* __restrict__ b2,
                                                const float* __restrict__ pw2w,
                                                const float* __restrict__ pw2b,
                                                const float* __restrict__ encw,
                                                const float* __restrict__ encb,
                                                const float* __restrict__ stats,
                                                float* __restrict__ h){
  int blk = blockIdx.x;
  int b  = blk >> 5;
  int t0 = (blk & 31) << 6;
  int tcnt = min(64, LSEQ - t0);
  __shared__ float vn[CO][64];
  __shared__ float p2[CO*CO];
  __shared__ float ew[CO*HD];
  __shared__ float u3[4][CO];
  __shared__ float hout[HD][65];
  int tid = threadIdx.x;
  float m = stats[96 + b], r = stats[112 + b];
  for (int i = tid; i < CO*CO; i += 256){
    int o = i & 31, c = i >> 5;
    p2[c*CO + o] = pw2w[o*CO + c];
  }
  for (int i = tid; i < CO*HD; i += 256) ew[i] = encw[i];
  for (int i = tid; i < CO*64; i += 256){
    int c = i >> 6, t = i & 63;
    float val = 0.f;
    if (t < tcnt) val = v[((long)(b*CO + c))*LSEQ + t0 + t];
    vn[c][t] = (val - m)*r*g2[c] + b2[c];
  }
  __syncthreads();
  int wv = tid >> 6, ln = tid & 63;
  for (int i = 0; i < 16; ++i){
    int tt = wv*16 + i;
    if (ln < CO){
      float acc = pw2b[ln];
      #pragma unroll
      for (int c = 0; c < CO; ++c) acc = fmaf(p2[c*CO + ln], vn[c][tt], acc);
      u3[wv][ln] = acc;
    }
    float hacc = encb[ln];
    #pragma unroll
    for (int c = 0; c < CO; ++c) hacc = fmaf(ew[c*HD + ln], u3[wv][c], hacc);
    hout[ln][tt] = hacc;
  }
  __syncthreads();
  for (int i = tid; i < HD*64; i += 256){
    int d = i >> 6, t = i & 63;
    if (t < tcnt) h[((long)(b*HD + d))*HSTR + t0 + t] = hout[d][t];
  }
}

// ---------------- S4D coefficients + K taps for ALL layers ----------------
// ktap[l][h][k] = 2 Re sum_n cd_n w_n^k  (k=0..63) — batch-independent, computed once.
__global__ void k_coef(const float* __restrict__ log_dt, const float* __restrict__ logA,
                       const float* __restrict__ Aim, const float* __restrict__ Cre,
                       const float* __restrict__ Cim, float* __restrict__ coef,
                       float* __restrict__ ktap){
  int blk = blockIdx.x;
  int l = blk >> 6, hh = blk & 63;
  int n = threadIdx.x;
  __shared__ float tk[64][65];
  float dt = expf(log_dt[l*HD + hh]);
  int idx = (l*HD + hh)*NST + n;
  float Ar = -expf(logA[idx]);
  float Ai = Aim[idx];
  float dr = Ar*dt, di = Ai*dt;
  float er = expf(dr);
  float wr = er*cosf(di), wi = er*sinf(di);
  float inv = 1.f/(Ar*Ar + Ai*Ai);
  float xr = wr - 1.f, xi = wi;
  float qr = (xr*Ar + xi*Ai)*inv;
  float qi = (xi*Ar - xr*Ai)*inv;
  float cr = Cre[idx], ci = Cim[idx];
  float cdr = cr*qr - ci*qi;
  float cdi = cr*qi + ci*qr;
  float* cl = coef + l*4*HD*NST;
  int hn = hh*NST + n;
  cl[hn]            = wr;
  cl[HD*NST + hn]   = wi;
  cl[2*HD*NST + hn] = cdr;
  cl[3*HD*NST + hn] = cdi;
  {
    float pr = cdr, pi = cdi;   // cd * w^0
    for (int k = 0; k < 64; ++k){
      tk[n][k] = pr;
      float t2 = pr*wr - pi*wi; pi = pr*wi + pi*wr; pr = t2;
    }
  }
  __syncthreads();
  {
    float s = 0.f;
    for (int m = 0; m < 64; ++m) s += tk[m][n];
    ktap[(l*HD + hh)*64 + n] = 2.f*s;
  }
}

// ---------------- S4D chunk-parallel scan ----------------
// v5: v4 structure (512 threads, 4 chunks/wave, acc[4], full E-table built once),
// but NO launch_bounds occupancy arg. Lesson of R1-R3: any min-waves hint makes the
// allocator cap VGPRs below the body's true pressure -> scratch spills (up to 3 GB/dispatch).
// R0 proved this compiler does NOT spill when left alone (224 VGPR, zero spill traffic).
// LDS 59,904 B -> 2 blocks/CU; if VGPR lands <=128 we get 4 waves/SIMD.
__global__ void __launch_bounds__(512) k_s4d(const float* __restrict__ h,
                                             const float* __restrict__ coef,
                                             const float* __restrict__ ktap,
                                             int layer, float* __restrict__ y){
  int blk = blockIdx.x;
  int b = blk >> 6, hh = blk & 63;
  __shared__ float u_s[2048];
  __shared__ float Eh[32*EROW*4];
  __shared__ float S_s[NCH*128];
  __shared__ float Kpad[128];
  __shared__ float wc[256];        // wr[64] | wi[64] | cdr[64] | cdi[64]
  int tid = threadIdx.x;
  int n = tid & 63, q = tid >> 6;  // lane, wave (0..7)
  const float* cl = coef + layer*4*HD*NST;
  int hn = hh*NST + n;
  float wr  = cl[hn];
  float wi  = cl[HD*NST + hn];
  const float* up = h + ((long)(b*HD + hh))*HSTR;

  // u load: 512 threads x 4 floats
  {
    int base = tid*4;
    if (base + 4 <= LSEQ){
      *(float4*)&u_s[base] = *(const float4*)(up + base);
    } else {
      #pragma unroll
      for (int k = 0; k < 4; ++k){
        int t = base + k;
        u_s[t] = (t < LSEQ) ? up[t] : 0.f;
      }
    }
  }
  if (q == 0){
    wc[n]       = wr;
    wc[64 + n]  = wi;
    wc[128 + n] = cl[2*HD*NST + hn];
    wc[192 + n] = cl[3*HD*NST + hn];
  }
  if (tid < 64) Kpad[tid] = 0.f;
  else if (tid < 128) Kpad[tid] = ktap[(layer*HD + hh)*64 + (tid - 64)];
  __syncthreads();

  // build FULL E-table: Eh[np][k-1] = float4(2cd_{2np}w^k, 2cd_{2np+1}w^k), k=1..64.
  // 512 threads: np=tid>>4 (0..31), par=(tid&1), seg=(tid&15)>>1 -> k in [seg*8+1, seg*8+8]
  {
    int np = tid >> 4, rr = tid & 15;
    int par = rr & 1, seg = rr >> 1;
    int s = np*2 + par;
    float ws = wc[s], wis = wc[64 + s], crs = wc[128 + s], cis = wc[192 + s];
    float ar = ws, ai = wis;
    #pragma unroll
    for (int t2i = 0; t2i < 3; ++t2i){ float t2 = ar*ar - ai*ai; ai = 2.f*ar*ai; ar = t2; }  // w^8
    float pr = 1.f, pi = 0.f;
    for (int k = 0; k < seg; ++k){ float t2 = pr*ar - pi*ai; pi = pr*ai + pi*ar; pr = t2; }   // w^(8seg)
    { float t2 = pr*ws - pi*wis; pi = pr*wis + pi*ws; pr = t2; }                              // w^(8seg+1)
    float* bp = &Eh[(np*EROW + seg*8)*4 + par*2];
    for (int k = 0; k < 8; ++k){
      float2 ev;
      ev.x = 2.f*(crs*pr - cis*pi);
      ev.y = 2.f*(crs*pi + cis*pr);
      *(float2*)bp = ev;
      float t2 = pr*ws - pi*wis; pi = pr*wis + pi*ws; pr = t2;
      bp += 4;
    }
  }

  // phase 1: per-chunk decayed input sums; wave q owns chunks q*4..q*4+3 (float4 Horner)
  int cbase = q*4;
  {
    float vr[4], vi[4];
    #pragma unroll
    for (int c = 0; c < 4; ++c){ vr[c] = 0.f; vi[c] = 0.f; }
    for (int j4 = 0; j4 < 64; j4 += 4){
      #pragma unroll
      for (int c = 0; c < 4; ++c){
        float4 uu = *(const float4*)&u_s[(cbase + c)*64 + j4];
        float xr = vr[c], xi = vi[c];
        float a_r = fmaf(wr, xr,  fmaf(-wi, xi,  uu.x));
        float a_i = fmaf(wr, xi,  wi*xr);
        float b_r = fmaf(wr, a_r, fmaf(-wi, a_i, uu.y));
        float b_i = fmaf(wr, a_i, wi*a_r);
        float c_r = fmaf(wr, b_r, fmaf(-wi, b_i, uu.z));
        float c_i = fmaf(wr, b_i, wi*b_r);
        vr[c] = fmaf(wr, c_r, fmaf(-wi, c_i, uu.w));
        vi[c] = fmaf(wr, c_i, wi*c_r);
      }
    }
    #pragma unroll
    for (int c = 0; c < 4; ++c){
      float2 sv = {vr[c], vi[c]};
      *(float2*)&S_s[(cbase + c)*128 + 2*n] = sv;
    }
  }
  __syncthreads();

  // phase 2 (wave 0): chunk-state exclusive scan (in place)
  if (q == 0){
    float ar = wr, ai = wi;
    #pragma unroll
    for (int s = 0; s < 6; ++s){ float t2 = ar*ar - ai*ai; ai = 2.f*ar*ai; ar = t2; }  // w^64
    float sr = 0.f, si = 0.f;
    for (int c = 0; c < NCH; ++c){
      float vr2 = S_s[c*128 + 2*n], vi2 = S_s[c*128 + 2*n + 1];
      float2 sv = {sr, si};
      *(float2*)&S_s[c*128 + 2*n] = sv;
      float nr = fmaf(ar, sr, fmaf(-ai, si, vr2));
      float ni = fmaf(ar, si, fmaf(ai, sr, vi2));
      sr = nr; si = ni;
    }
  }
  __syncthreads();

  // phase 3: state contributions (np-outer; 1 lane-varying e-read feeds 4 broadcast S-reads)
  float acc[4];
  #pragma unroll
  for (int c = 0; c < 4; ++c) acc[c] = 0.f;
  for (int np = 0; np < 32; ++np){
    float4 e = *(const float4*)&Eh[(np*EROW + n)*4];
    #pragma unroll
    for (int c = 0; c < 4; ++c){
      float4 s = *(const float4*)&S_s[(cbase + c)*128 + np*4];
      acc[c] = fmaf(e.x,s.x, fmaf(-e.y,s.y, fmaf(e.z,s.z, fmaf(-e.w,s.w, acc[c]))));
    }
  }

  // in-chunk convolution (taps shared across the thread's 4 chunk-outputs) + store
  const float* Kb = &Kpad[64 + n];
  for (int j4 = 0; j4 < 64; j4 += 4){
    float k0 = Kb[-j4], k1 = Kb[-j4-1], k2 = Kb[-j4-2], k3 = Kb[-j4-3];
    #pragma unroll
    for (int c = 0; c < 4; ++c){
      float4 u4 = *(const float4*)&u_s[(cbase + c)*64 + j4];
      acc[c] = fmaf(k0,u4.x, fmaf(k1,u4.y, fmaf(k2,u4.z, fmaf(k3,u4.w, acc[c]))));
    }
  }
  float* yo = y + ((long)(b*HD + hh))*HSTR;
  #pragma unroll
  for (int c = 0; c < 4; ++c){
    int t = (cbase + c)*64 + n;
    if (t < LSEQ) yo[t] = acc[c];
  }
}

// ---------------- S4D post: register-tiled GEMM + GLU + residual + LN ----------------
__global__ void __launch_bounds__(256) k_post(const float* __restrict__ y,
                                              float* __restrict__ h,
                                              const float* __restrict__ D,
                                              const float* __restrict__ ow,
                                              const float* __restrict__ ob,
                                              const float* __restrict__ lng,
                                              const float* __restrict__ lnb,
                                              int layer){
  int blk = blockIdx.x;
  int b  = blk >> 5;
  int t0 = (blk & 31) << 6;
  __shared__ float Ws[64*128];     // [c][o]
  __shared__ float Ys[64*68];      // [c][t]; reused as z-buffer
  __shared__ float mstat[64], rstat[64];
  int tid = threadIdx.x;
  const float* owp = ow + layer*2*HD*HD;
  const float* obp = ob + layer*2*HD;
  {
    int o = tid >> 1, cs = (tid & 1)*32;
    const float* wrow = owp + o*HD + cs;
    #pragma unroll
    for (int k = 0; k < 8; ++k){
      float4 w4 = *(const float4*)(wrow + k*4);
      Ws[(cs + k*4 + 0)*128 + o] = w4.x;
      Ws[(cs + k*4 + 1)*128 + o] = w4.y;
      Ws[(cs + k*4 + 2)*128 + o] = w4.z;
      Ws[(cs + k*4 + 3)*128 + o] = w4.w;
    }
  }
  {
    int c = tid >> 2, qq = tid & 3;
    float dl = D[layer*HD + c];
    const float* yrow = y + ((long)(b*HD + c))*HSTR + t0 + qq*16;
    const float* hrow = h + ((long)(b*HD + c))*HSTR + t0 + qq*16;
    #pragma unroll
    for (int k = 0; k < 4; ++k){
      float4 yv = *(const float4*)(yrow + k*4);
      float4 hv = *(const float4*)(hrow + k*4);
      float4 g4;
      g4.x = gelu_(fmaf(hv.x, dl, yv.x));
      g4.y = gelu_(fmaf(hv.y, dl, yv.y));
      g4.z = gelu_(fmaf(hv.z, dl, yv.z));
      g4.w = gelu_(fmaf(hv.w, dl, yv.w));
      *(float4*)&Ys[c*68 + qq*16 + k*4] = g4;
    }
  }
  __syncthreads();
  int og = tid >> 4, tg = tid & 15;
  int o0 = og*4, tt0 = tg*4;
  float accA[4][4], accG[4][4];
  #pragma unroll
  for (int i = 0; i < 4; ++i){
    float ba = obp[o0 + i], bg = obp[64 + o0 + i];
    #pragma unroll
    for (int j = 0; j < 4; ++j){ accA[i][j] = ba; accG[i][j] = bg; }
  }
  for (int c = 0; c < 64; ++c){
    float4 wa = *(const float4*)&Ws[c*128 + o0];
    float4 wg = *(const float4*)&Ws[c*128 + 64 + o0];
    float4 yv = *(const float4*)&Ys[c*68 + tt0];
    float yvv[4] = {yv.x, yv.y, yv.z, yv.w};
    float wav[4] = {wa.x, wa.y, wa.z, wa.w};
    float wgv[4] = {wg.x, wg.y, wg.z, wg.w};
    #pragma unroll
    for (int i = 0; i < 4; ++i){
      #pragma unroll
      for (int j = 0; j < 4; ++j){
        accA[i][j] = fmaf(wav[i], yvv[j], accA[i][j]);
        accG[i][j] = fmaf(wgv[i], yvv[j], accG[i][j]);
      }
    }
  }
  __syncthreads();
  float r[4][4];
  #pragma unroll
  for (int i = 0; i < 4; ++i){
    int c = o0 + i;
    const float* hrow = h + ((long)(b*HD + c))*HSTR + t0 + tt0;
    #pragma unroll
    for (int j = 0; j < 4; ++j){
      int t = t0 + tt0 + j;
      float hold = (t < LSEQ) ? hrow[j] : 0.f;
      float z = accA[i][j] * sigm(accG[i][j]);
      r[i][j] = z + hold;
    }
    float4 rr = {r[i][0], r[i][1], r[i][2], r[i][3]};
    *(float4*)&Ys[c*68 + tt0] = rr;
  }
  __syncthreads();
  if (tid < 64){
    float s1 = 0.f, s2 = 0.f;
    for (int c = 0; c < 64; ++c){
      float v = Ys[c*68 + tid];
      s1 += v; s2 += v*v;
    }
    float m = s1 * (1.f/64.f);
    float var = fmaf(-m, m, s2 * (1.f/64.f));
    mstat[tid] = m;
    rstat[tid] = rsqrtf(var + EPSF);
  }
  __syncthreads();
  #pragma unroll
  for (int i = 0; i < 4; ++i){
    int c = o0 + i;
    float gl = lng[layer*HD + c], bl = lnb[layer*HD + c];
    float* hrow = h + ((long)(b*HD + c))*HSTR + t0 + tt0;
    if (t0 + tt0 + 3 < LSEQ){
      float4 o4v;
      o4v.x = fmaf((r[i][0] - mstat[tt0+0])*rstat[tt0+0], gl, bl);
      o4v.y = fmaf((r[i][1] - mstat[tt0+1])*rstat[tt0+1], gl, bl);
      o4v.z = fmaf((r[i][2] - mstat[tt0+2])*rstat[tt0+2], gl, bl);
      o4v.w = fmaf((r[i][3] - mstat[tt0+3])*rstat[tt0+3], gl, bl);
      *(float4*)hrow = o4v;
    } else {
      #pragma unroll
      for (int j = 0; j < 4; ++j){
        int t = t0 + tt0 + j;
        if (t < LSEQ) hrow[j] = fmaf((r[i][j] - mstat[tt0+j])*rstat[tt0+j], gl, bl);
      }
    }
  }
}

// ---------------- Decoder: register-blocked, weight-reuse GEMM ----------------
__global__ void __launch_bounds__(320) k_dec(const float* __restrict__ h,
                                             const float* __restrict__ w,
                                             const float* __restrict__ bias,
                                             float* __restrict__ out){
  int blk = blockIdx.x;
  int b  = blk >> 6;
  int t0 = (blk & 63) << 5;
  __shared__ float hl[HD][32];
  int tid = threadIdx.x;
  for (int i = tid; i < HD*32; i += 320){
    int d = i >> 5, t = i & 31;
    int tt = t0 + t;
    hl[d][t] = (tt < LSEQ) ? h[((long)(b*HD + d))*HSTR + tt] : 0.f;
  }
  __syncthreads();
  int o4 = tid % 160, th = tid / 160;
  int tb = th * 16;
  float4 acc[16];
  const float4 b4 = *(const float4*)(bias + o4*4);
  #pragma unroll
  for (int i = 0; i < 16; ++i) acc[i] = b4;
  const float* wp = w + o4*4;
  for (int d = 0; d < HD; ++d){
    float4 w4 = *(const float4*)(wp + (long)d*DOUT);
    #pragma unroll
    for (int ii = 0; ii < 4; ++ii){
      float4 h4 = *(const float4*)&hl[d][tb + ii*4];
      float hvv[4] = {h4.x, h4.y, h4.z, h4.w};
      #pragma unroll
      for (int jj = 0; jj < 4; ++jj){
        int i = ii*4 + jj;
        acc[i].x = fmaf(hvv[jj], w4.x, acc[i].x);
        acc[i].y = fmaf(hvv[jj], w4.y, acc[i].y);
        acc[i].z = fmaf(hvv[jj], w4.z, acc[i].z);
        acc[i].w = fmaf(hvv[jj], w4.w, acc[i].w);
      }
    }
  }
  #pragma unroll
  for (int i = 0; i < 16; ++i){
    int t = t0 + tb + i;
    if (t < LSEQ) *(float4*)(out + ((long)(b*LSEQ) + t)*DOUT + o4*4) = acc[i];
  }
}

extern "C" void kernel_launch(void* const* d_in, const int* in_sizes, int n_in,
                              void* d_out, int out_size, void* d_ws, size_t ws_size,
                              hipStream_t stream){
  const float* x     = (const float*)d_in[0];
  const float* pw1_w = (const float*)d_in[1];
  const float* pw1_b = (const float*)d_in[2];
  const float* gn1_g = (const float*)d_in[3];
  const float* gn1_b = (const float*)d_in[4];
  const float* dw_w  = (const float*)d_in[5];
  const float* dw_b  = (const float*)d_in[6];
  const float* gn2_g = (const float*)d_in[7];
  const float* gn2_b = (const float*)d_in[8];
  const float* pw2_w = (const float*)d_in[9];
  const float* pw2_b = (const float*)d_in[10];
  const float* enc_w = (const float*)d_in[11];
  const float* enc_b = (const float*)d_in[12];
  const float* log_dt= (const float*)d_in[13];
  const float* logA  = (const float*)d_in[14];
  const float* Aim   = (const float*)d_in[15];
  const float* Cre   = (const float*)d_in[16];
  const float* Cim   = (const float*)d_in[17];
  const float* Dp    = (const float*)d_in[18];
  const float* owp   = (const float*)d_in[19];
  const float* obp   = (const float*)d_in[20];
  const float* lng   = (const float*)d_in[21];
  const float* lnb   = (const float*)d_in[22];
  const float* dec_w = (const float*)d_in[23];
  const float* dec_b = (const float*)d_in[24];
  float* out = (float*)d_out;

  float* ws   = (float*)d_ws;
  float* u1   = ws;
  float* u2   = u1 + 2097152;
  float* vv   = u2 + 1048576;
  float* hbuf = vv + 1033728;
  float* coef = hbuf + 2097152;
  float* stats= coef + 131072;
  float* ktap = stats + 128;       // NLAY*HD*64 = 32768 floats
  float* ybuf = u1;

  hipMemsetAsync(stats, 0, 128*sizeof(float), stream);
  k_coef<<<NLAY*HD, 64, 0, stream>>>(log_dt, logA, Aim, Cre, Cim, coef, ktap);
  k_pw1<<<BB*64, 256, 0, stream>>>(x, pw1_w, pw1_b, u1, stats);
  k_gnstat<<<1, 64, 0, stream>>>(stats, 0, (float)(CO*TFULL));
  k_glu_silu<<<BB*32, 256, 0, stream>>>(u1, gn1_g, gn1_b, stats, u2);
  k_dconv<<<BB*CO, 256, 0, stream>>>(u2, dw_w, dw_b, vv, stats);
  k_gnstat<<<1, 64, 0, stream>>>(stats, 1, (float)(CO*LSEQ));
  k_pw2enc<<<BB*32, 256, 0, stream>>>(vv, gn2_g, gn2_b, pw2_w, pw2_b, enc_w, enc_b, stats, hbuf);
  for (int l = 0; l < NLAY; ++l){
    k_s4d<<<BB*HD, 512, 0, stream>>>(hbuf, coef, ktap, l, ybuf);
    k_post<<<BB*32, 256, 0, stream>>>(ybuf, hbuf, Dp, owp, obp, lng, lnb, l);
  }
  k_dec<<<BB*64, 320, 0, stream>>>(hbuf, dec_w, dec_b, out);
}

// Round 5
// 783.873 us; speedup vs baseline: 9.9496x; 7.6087x over previous
//
#include <hip/hip_runtime.h>
#include <math.h>

#define BB   16
#define TFULL 4096
#define T2   2048
#define LSEQ 2019
#define HSTR 2048
#define CIN  64
#define CO   32
#define HD   64
#define NST  64
#define NLAY 8
#define DOUT 640
#define EPSF 1e-5f
#define NCH  32
#define CHL  64
#define EROW 66   // padded row stride (entries, 16B each) for E-table

static __device__ __forceinline__ float sigm(float x){ return 1.f/(1.f + __expf(-x)); }
static __device__ __forceinline__ float gelu_(float x){ return 0.5f*x*(1.f + erff(x*0.7071067811865475f)); }

// ---------------- Stage A: pw1 conv + GN1 partial stats ----------------
__global__ void __launch_bounds__(256) k_pw1(const float* __restrict__ x,
                                             const float* __restrict__ w,
                                             const float* __restrict__ bias,
                                             float* __restrict__ u1,
                                             float* __restrict__ stats){
  int blk = blockIdx.x;
  int b  = blk >> 6;
  int t0 = (blk & 63) << 6;
  __shared__ float xs[CIN][64];
  __shared__ float wsm[CO*CIN];
  __shared__ float red[8];
  int tid = threadIdx.x;
  for (int i = tid; i < CIN*64; i += 256){
    int c = i >> 6, t = i & 63;
    xs[c][t] = x[((long)(b*CIN + c))*TFULL + t0 + t];
  }
  for (int i = tid; i < CO*CIN; i += 256) wsm[i] = w[i];
  __syncthreads();
  int t  = tid & 63;
  int o0 = tid >> 6;
  float lsum = 0.f, lsq = 0.f;
  for (int o = o0; o < CO; o += 4){
    float acc = bias[o];
    #pragma unroll
    for (int c = 0; c < CIN; ++c) acc = fmaf(wsm[o*CIN + c], xs[c][t], acc);
    u1[((long)(b*CO + o))*TFULL + t0 + t] = acc;
    lsum += acc; lsq += acc*acc;
  }
  #pragma unroll
  for (int off = 32; off; off >>= 1){ lsum += __shfl_down(lsum, off); lsq += __shfl_down(lsq, off); }
  if ((tid & 63) == 0){ red[tid>>6] = lsum; red[4 + (tid>>6)] = lsq; }
  __syncthreads();
  if (tid == 0){
    atomicAdd(&stats[b],      red[0]+red[1]+red[2]+red[3]);
    atomicAdd(&stats[16 + b], red[4]+red[5]+red[6]+red[7]);
  }
}

__global__ void k_gnstat(float* __restrict__ stats, int which, float cnt){
  int b = threadIdx.x;
  if (b < BB){
    int o = which * 64;
    float m = stats[o + b] / cnt;
    float v = stats[o + 16 + b] / cnt - m*m;
    stats[o + 32 + b] = m;
    stats[o + 48 + b] = rsqrtf(v + EPSF);
  }
}

// ---------------- Stage A3: GN1 apply + GLU(time) + SiLU ----------------
__global__ void __launch_bounds__(256) k_glu_silu(const float* __restrict__ u1,
                                                  const float* __restrict__ g,
                                                  const float* __restrict__ bb,
                                                  const float* __restrict__ stats,
                                                  float* __restrict__ u2){
  int blk = blockIdx.x;
  int b  = blk >> 5;
  int t0 = (blk & 31) << 6;
  float m = stats[32 + b], r = stats[48 + b];
  int tid = threadIdx.x;
  int t = t0 + (tid & 63);
  for (int c = tid >> 6; c < CO; c += 4){
    long base = ((long)(b*CO + c))*TFULL;
    float a  = u1[base + t];
    float bv = u1[base + t + T2];
    float gc = g[c], bc = bb[c];
    a  = (a  - m)*r*gc + bc;
    bv = (bv - m)*r*gc + bc;
    float z = a * sigm(bv);
    z = z * sigm(z);
    u2[((long)(b*CO + c))*T2 + t] = z;
  }
}

// ---------------- Stage B1: depthwise conv (K=32, pad 1) + GN2 partial stats ----------------
__global__ void __launch_bounds__(256) k_dconv(const float* __restrict__ u2,
                                               const float* __restrict__ w,
                                               const float* __restrict__ bias,
                                               float* __restrict__ v,
                                               float* __restrict__ stats){
  int blk = blockIdx.x;
  int b = blk >> 5, c = blk & 31;
  __shared__ float row[T2 + 2];
  __shared__ float red[8];
  int tid = threadIdx.x;
  if (tid == 0){ row[0] = 0.f; row[T2 + 1] = 0.f; }
  const float* src = u2 + ((long)(b*CO + c))*T2;
  for (int i = tid; i < T2; i += 256) row[1 + i] = src[i];
  __syncthreads();
  float wk[32];
  #pragma unroll
  for (int k = 0; k < 32; ++k) wk[k] = w[c*32 + k];
  float bc = bias[c];
  float lsum = 0.f, lsq = 0.f;
  float* dst = v + ((long)(b*CO + c))*LSEQ;
  for (int t = tid; t < LSEQ; t += 256){
    float acc = bc;
    #pragma unroll
    for (int k = 0; k < 32; ++k) acc = fmaf(wk[k], row[t + k], acc);
    dst[t] = acc;
    lsum += acc; lsq += acc*acc;
  }
  #pragma unroll
  for (int off = 32; off; off >>= 1){ lsum += __shfl_down(lsum, off); lsq += __shfl_down(lsq, off); }
  if ((tid & 63) == 0){ red[tid>>6] = lsum; red[4 + (tid>>6)] = lsq; }
  __syncthreads();
  if (tid == 0){
    atomicAdd(&stats[64 + b], red[0]+red[1]+red[2]+red[3]);
    atomicAdd(&stats[80 + b], red[4]+red[5]+red[6]+red[7]);
  }
}

// ---------------- Stage B3: GN2 apply + pw2 + encoder -> h (B,HD,HSTR) ----------------
__global__ void __launch_bounds__(256) k_pw2enc(const float* __restrict__ v,
                                                const float* __restrict__ g2,
                                                const float* __restrict__ b2,
                                                const float* __restrict__ pw2w,
                                                const float* __restrict__ pw2b,
                                                const float* __restrict__ encw,
                                                const float* __restrict__ encb,
                                                const float* __restrict__ stats,
                                                float* __restrict__ h){
  int blk = blockIdx.x;
  int b  = blk >> 5;
  int t0 = (blk & 31) << 6;
  int tcnt = min(64, LSEQ - t0);
  __shared__ float vn[CO][64];
  __shared__ float p2[CO*CO];
  __shared__ float ew[CO*HD];
  __shared__ float u3[4][CO];
  __shared__ float hout[HD][65];
  int tid = threadIdx.x;
  float m = stats[96 + b], r = stats[112 + b];
  for (int i = tid; i < CO*CO; i += 256){
    int o = i & 31, c = i >> 5;
    p2[c*CO + o] = pw2w[o*CO + c];
  }
  for (int i = tid; i < CO*HD; i += 256) ew[i] = encw[i];
  for (int i = tid; i < CO*64; i += 256){
    int c = i >> 6, t = i & 63;
    float val = 0.f;
    if (t < tcnt) val = v[((long)(b*CO + c))*LSEQ + t0 + t];
    vn[c][t] = (val - m)*r*g2[c] + b2[c];
  }
  __syncthreads();
  int wv = tid >> 6, ln = tid & 63;
  for (int i = 0; i < 16; ++i){
    int tt = wv*16 + i;
    if (ln < CO){
      float acc = pw2b[ln];
      #pragma unroll
      for (int c = 0; c < CO; ++c) acc = fmaf(p2[c*CO + ln], vn[c][tt], acc);
      u3[wv][ln] = acc;
    }
    float hacc = encb[ln];
    #pragma unroll
    for (int c = 0; c < CO; ++c) hacc = fmaf(ew[c*HD + ln], u3[wv][c], hacc);
    hout[ln][tt] = hacc;
  }
  __syncthreads();
  for (int i = tid; i < HD*64; i += 256){
    int d = i >> 6, t = i & 63;
    if (t < tcnt) h[((long)(b*HD + d))*HSTR + t0 + t] = hout[d][t];
  }
}

// ---------------- S4D coefficients + K taps for ALL layers ----------------
// ktap[l][h][k] = 2 Re sum_n cd_n w_n^k  (k=0..63) — batch-independent, computed once.
__global__ void k_coef(const float* __restrict__ log_dt, const float* __restrict__ logA,
                       const float* __restrict__ Aim, const float* __restrict__ Cre,
                       const float* __restrict__ Cim, float* __restrict__ coef,
                       float* __restrict__ ktap){
  int blk = blockIdx.x;
  int l = blk >> 6, hh = blk & 63;
  int n = threadIdx.x;
  __shared__ float tk[64][65];
  float dt = expf(log_dt[l*HD + hh]);
  int idx = (l*HD + hh)*NST + n;
  float Ar = -expf(logA[idx]);
  float Ai = Aim[idx];
  float dr = Ar*dt, di = Ai*dt;
  float er = expf(dr);
  float wr = er*cosf(di), wi = er*sinf(di);
  float inv = 1.f/(Ar*Ar + Ai*Ai);
  float xr = wr - 1.f, xi = wi;
  float qr = (xr*Ar + xi*Ai)*inv;
  float qi = (xi*Ar - xr*Ai)*inv;
  float cr = Cre[idx], ci = Cim[idx];
  float cdr = cr*qr - ci*qi;
  float cdi = cr*qi + ci*qr;
  float* cl = coef + l*4*HD*NST;
  int hn = hh*NST + n;
  cl[hn]            = wr;
  cl[HD*NST + hn]   = wi;
  cl[2*HD*NST + hn] = cdr;
  cl[3*HD*NST + hn] = cdi;
  {
    float pr = cdr, pi = cdi;   // cd * w^0
    for (int k = 0; k < 64; ++k){
      tk[n][k] = pr;
      float t2 = pr*wr - pi*wi; pi = pr*wi + pi*wr; pr = t2;
    }
  }
  __syncthreads();
  {
    float s = 0.f;
    for (int m = 0; m < 64; ++m) s += tk[m][n];
    ktap[(l*HD + hh)*64 + n] = 2.f*s;
  }
}

// ---------------- S4D chunk-parallel scan ----------------
// v6: v4 body, but LDS padded past 81,920 B so only ONE 512-thread block fits per CU.
// Rationale (R1-R4 post-mortems): whenever the backend's occupancy target (from a
// launch_bounds hint OR from "LDS allows 2 blocks") sits below the body's true register
// pressure, it spills to scratch rather than yielding occupancy (0.4-3 GB/dispatch).
// Forcing 1 block/CU sets the target to 2 waves/SIMD -> full 256-VGPR budget, which the
// body fits. #pragma unroll 2 on the hot loops bounds software-pipelining depth (the
// in-flight float4 clusters that inflated pressure in R2/R4).
__global__ void __launch_bounds__(512) k_s4d(const float* __restrict__ h,
                                             const float* __restrict__ coef,
                                             const float* __restrict__ ktap,
                                             int layer, float* __restrict__ y){
  int blk = blockIdx.x;
  int b = blk >> 6, hh = blk & 63;
  __shared__ float u_s[7680];      // 2048 used; rest pads LDS to 82,432 B (forces 1 block/CU)
  __shared__ float Eh[32*EROW*4];
  __shared__ float S_s[NCH*128];
  __shared__ float Kpad[128];
  __shared__ float wc[256];        // wr[64] | wi[64] | cdr[64] | cdi[64]
  int tid = threadIdx.x;
  int n = tid & 63, q = tid >> 6;  // lane, wave (0..7)
  const float* cl = coef + layer*4*HD*NST;
  int hn = hh*NST + n;
  float wr  = cl[hn];
  float wi  = cl[HD*NST + hn];
  const float* up = h + ((long)(b*HD + hh))*HSTR;

  // u load: 512 threads x 4 floats
  {
    int base = tid*4;
    if (base + 4 <= LSEQ){
      *(float4*)&u_s[base] = *(const float4*)(up + base);
    } else {
      #pragma unroll
      for (int k = 0; k < 4; ++k){
        int t = base + k;
        u_s[t] = (t < LSEQ) ? up[t] : 0.f;
      }
    }
  }
  if (q == 0){
    wc[n]       = wr;
    wc[64 + n]  = wi;
    wc[128 + n] = cl[2*HD*NST + hn];
    wc[192 + n] = cl[3*HD*NST + hn];
  }
  if (tid < 64) Kpad[tid] = 0.f;
  else if (tid < 128) Kpad[tid] = ktap[(layer*HD + hh)*64 + (tid - 64)];
  __syncthreads();

  // build FULL E-table: Eh[np][k-1] = float4(2cd_{2np}w^k, 2cd_{2np+1}w^k), k=1..64.
  // 512 threads: np=tid>>4 (0..31), par=(tid&1), seg=(tid&15)>>1 -> k in [seg*8+1, seg*8+8]
  {
    int np = tid >> 4, rr = tid & 15;
    int par = rr & 1, seg = rr >> 1;
    int s = np*2 + par;
    float ws = wc[s], wis = wc[64 + s], crs = wc[128 + s], cis = wc[192 + s];
    float ar = ws, ai = wis;
    #pragma unroll
    for (int t2i = 0; t2i < 3; ++t2i){ float t2 = ar*ar - ai*ai; ai = 2.f*ar*ai; ar = t2; }  // w^8
    float pr = 1.f, pi = 0.f;
    for (int k = 0; k < seg; ++k){ float t2 = pr*ar - pi*ai; pi = pr*ai + pi*ar; pr = t2; }   // w^(8seg)
    { float t2 = pr*ws - pi*wis; pi = pr*wis + pi*ws; pr = t2; }                              // w^(8seg+1)
    float* bp = &Eh[(np*EROW + seg*8)*4 + par*2];
    for (int k = 0; k < 8; ++k){
      float2 ev;
      ev.x = 2.f*(crs*pr - cis*pi);
      ev.y = 2.f*(crs*pi + cis*pr);
      *(float2*)bp = ev;
      float t2 = pr*ws - pi*wis; pi = pr*wis + pi*ws; pr = t2;
      bp += 4;
    }
  }

  // phase 1: per-chunk decayed input sums; wave q owns chunks q*4..q*4+3 (float4 Horner)
  int cbase = q*4;
  {
    float vr[4], vi[4];
    #pragma unroll
    for (int c = 0; c < 4; ++c){ vr[c] = 0.f; vi[c] = 0.f; }
    #pragma unroll 2
    for (int j4 = 0; j4 < 64; j4 += 4){
      #pragma unroll
      for (int c = 0; c < 4; ++c){
        float4 uu = *(const float4*)&u_s[(cbase + c)*64 + j4];
        float xr = vr[c], xi = vi[c];
        float a_r = fmaf(wr, xr,  fmaf(-wi, xi,  uu.x));
        float a_i = fmaf(wr, xi,  wi*xr);
        float b_r = fmaf(wr, a_r, fmaf(-wi, a_i, uu.y));
        float b_i = fmaf(wr, a_i, wi*a_r);
        float c_r = fmaf(wr, b_r, fmaf(-wi, b_i, uu.z));
        float c_i = fmaf(wr, b_i, wi*b_r);
        vr[c] = fmaf(wr, c_r, fmaf(-wi, c_i, uu.w));
        vi[c] = fmaf(wr, c_i, wi*c_r);
      }
    }
    #pragma unroll
    for (int c = 0; c < 4; ++c){
      float2 sv = {vr[c], vi[c]};
      *(float2*)&S_s[(cbase + c)*128 + 2*n] = sv;
    }
  }
  __syncthreads();

  // phase 2 (wave 0): chunk-state exclusive scan (in place)
  if (q == 0){
    float ar = wr, ai = wi;
    #pragma unroll
    for (int s = 0; s < 6; ++s){ float t2 = ar*ar - ai*ai; ai = 2.f*ar*ai; ar = t2; }  // w^64
    float sr = 0.f, si = 0.f;
    for (int c = 0; c < NCH; ++c){
      float vr2 = S_s[c*128 + 2*n], vi2 = S_s[c*128 + 2*n + 1];
      float2 sv = {sr, si};
      *(float2*)&S_s[c*128 + 2*n] = sv;
      float nr = fmaf(ar, sr, fmaf(-ai, si, vr2));
      float ni = fmaf(ar, si, fmaf(ai, sr, vi2));
      sr = nr; si = ni;
    }
  }
  __syncthreads();

  // phase 3: state contributions (np-outer; 1 lane-varying e-read feeds 4 broadcast S-reads)
  float acc[4];
  #pragma unroll
  for (int c = 0; c < 4; ++c) acc[c] = 0.f;
  #pragma unroll 2
  for (int np = 0; np < 32; ++np){
    float4 e = *(const float4*)&Eh[(np*EROW + n)*4];
    #pragma unroll
    for (int c = 0; c < 4; ++c){
      float4 s = *(const float4*)&S_s[(cbase + c)*128 + np*4];
      acc[c] = fmaf(e.x,s.x, fmaf(-e.y,s.y, fmaf(e.z,s.z, fmaf(-e.w,s.w, acc[c]))));
    }
  }

  // in-chunk convolution (taps shared across the thread's 4 chunk-outputs) + store
  const float* Kb = &Kpad[64 + n];
  #pragma unroll 2
  for (int j4 = 0; j4 < 64; j4 += 4){
    float k0 = Kb[-j4], k1 = Kb[-j4-1], k2 = Kb[-j4-2], k3 = Kb[-j4-3];
    #pragma unroll
    for (int c = 0; c < 4; ++c){
      float4 u4 = *(const float4*)&u_s[(cbase + c)*64 + j4];
      acc[c] = fmaf(k0,u4.x, fmaf(k1,u4.y, fmaf(k2,u4.z, fmaf(k3,u4.w, acc[c]))));
    }
  }
  float* yo = y + ((long)(b*HD + hh))*HSTR;
  #pragma unroll
  for (int c = 0; c < 4; ++c){
    int t = (cbase + c)*64 + n;
    if (t < LSEQ) yo[t] = acc[c];
  }
}

// ---------------- S4D post: register-tiled GEMM + GLU + residual + LN ----------------
__global__ void __launch_bounds__(256) k_post(const float* __restrict__ y,
                                              float* __restrict__ h,
                                              const float* __restrict__ D,
                                              const float* __restrict__ ow,
                                              const float* __restrict__ ob,
                                              const float* __restrict__ lng,
                                              const float* __restrict__ lnb,
                                              int layer){
  int blk = blockIdx.x;
  int b  = blk >> 5;
  int t0 = (blk & 31) << 6;
  __shared__ float Ws[64*128];     // [c][o]
  __shared__ float Ys[64*68];      // [c][t]; reused as z-buffer
  __shared__ float mstat[64], rstat[64];
  int tid = threadIdx.x;
  const float* owp = ow + layer*2*HD*HD;
  const float* obp = ob + layer*2*HD;
  {
    int o = tid >> 1, cs = (tid & 1)*32;
    const float* wrow = owp + o*HD + cs;
    #pragma unroll
    for (int k = 0; k < 8; ++k){
      float4 w4 = *(const float4*)(wrow + k*4);
      Ws[(cs + k*4 + 0)*128 + o] = w4.x;
      Ws[(cs + k*4 + 1)*128 + o] = w4.y;
      Ws[(cs + k*4 + 2)*128 + o] = w4.z;
      Ws[(cs + k*4 + 3)*128 + o] = w4.w;
    }
  }
  {
    int c = tid >> 2, qq = tid & 3;
    float dl = D[layer*HD + c];
    const float* yrow = y + ((long)(b*HD + c))*HSTR + t0 + qq*16;
    const float* hrow = h + ((long)(b*HD + c))*HSTR + t0 + qq*16;
    #pragma unroll
    for (int k = 0; k < 4; ++k){
      float4 yv = *(const float4*)(yrow + k*4);
      float4 hv = *(const float4*)(hrow + k*4);
      float4 g4;
      g4.x = gelu_(fmaf(hv.x, dl, yv.x));
      g4.y = gelu_(fmaf(hv.y, dl, yv.y));
      g4.z = gelu_(fmaf(hv.z, dl, yv.z));
      g4.w = gelu_(fmaf(hv.w, dl, yv.w));
      *(float4*)&Ys[c*68 + qq*16 + k*4] = g4;
    }
  }
  __syncthreads();
  int og = tid >> 4, tg = tid & 15;
  int o0 = og*4, tt0 = tg*4;
  float accA[4][4], accG[4][4];
  #pragma unroll
  for (int i = 0; i < 4; ++i){
    float ba = obp[o0 + i], bg = obp[64 + o0 + i];
    #pragma unroll
    for (int j = 0; j < 4; ++j){ accA[i][j] = ba; accG[i][j] = bg; }
  }
  for (int c = 0; c < 64; ++c){
    float4 wa = *(const float4*)&Ws[c*128 + o0];
    float4 wg = *(const float4*)&Ws[c*128 + 64 + o0];
    float4 yv = *(const float4*)&Ys[c*68 + tt0];
    float yvv[4] = {yv.x, yv.y, yv.z, yv.w};
    float wav[4] = {wa.x, wa.y, wa.z, wa.w};
    float wgv[4] = {wg.x, wg.y, wg.z, wg.w};
    #pragma unroll
    for (int i = 0; i < 4; ++i){
      #pragma unroll
      for (int j = 0; j < 4; ++j){
        accA[i][j] = fmaf(wav[i], yvv[j], accA[i][j]);
        accG[i][j] = fmaf(wgv[i], yvv[j], accG[i][j]);
      }
    }
  }
  __syncthreads();
  float r[4][4];
  #pragma unroll
  for (int i = 0; i < 4; ++i){
    int c = o0 + i;
    const float* hrow = h + ((long)(b*HD + c))*HSTR + t0 + tt0;
    #pragma unroll
    for (int j = 0; j < 4; ++j){
      int t = t0 + tt0 + j;
      float hold = (t < LSEQ) ? hrow[j] : 0.f;
      float z = accA[i][j] * sigm(accG[i][j]);
      r[i][j] = z + hold;
    }
    float4 rr = {r[i][0], r[i][1], r[i][2], r[i][3]};
    *(float4*)&Ys[c*68 + tt0] = rr;
  }
  __syncthreads();
  if (tid < 64){
    float s1 = 0.f, s2 = 0.f;
    for (int c = 0; c < 64; ++c){
      float v = Ys[c*68 + tid];
      s1 += v; s2 += v*v;
    }
    float m = s1 * (1.f/64.f);
    float var = fmaf(-m, m, s2 * (1.f/64.f));
    mstat[tid] = m;
    rstat[tid] = rsqrtf(var + EPSF);
  }
  __syncthreads();
  #pragma unroll
  for (int i = 0; i < 4; ++i){
    int c = o0 + i;
    float gl = lng[layer*HD + c], bl = lnb[layer*HD + c];
    float* hrow = h + ((long)(b*HD + c))*HSTR + t0 + tt0;
    if (t0 + tt0 + 3 < LSEQ){
      float4 o4v;
      o4v.x = fmaf((r[i][0] - mstat[tt0+0])*rstat[tt0+0], gl, bl);
      o4v.y = fmaf((r[i][1] - mstat[tt0+1])*rstat[tt0+1], gl, bl);
      o4v.z = fmaf((r[i][2] - mstat[tt0+2])*rstat[tt0+2], gl, bl);
      o4v.w = fmaf((r[i][3] - mstat[tt0+3])*rstat[tt0+3], gl, bl);
      *(float4*)hrow = o4v;
    } else {
      #pragma unroll
      for (int j = 0; j < 4; ++j){
        int t = t0 + tt0 + j;
        if (t < LSEQ) hrow[j] = fmaf((r[i][j] - mstat[tt0+j])*rstat[tt0+j], gl, bl);
      }
    }
  }
}

// ---------------- Decoder: register-blocked, weight-reuse GEMM ----------------
__global__ void __launch_bounds__(320) k_dec(const float* __restrict__ h,
                                             const float* __restrict__ w,
                                             const float* __restrict__ bias,
                                             float* __restrict__ out){
  int blk = blockIdx.x;
  int b  = blk >> 6;
  int t0 = (blk & 63) << 5;
  __shared__ float hl[HD][32];
  int tid = threadIdx.x;
  for (int i = tid; i < HD*32; i += 320){
    int d = i >> 5, t = i & 31;
    int tt = t0 + t;
    hl[d][t] = (tt < LSEQ) ? h[((long)(b*HD + d))*HSTR + tt] : 0.f;
  }
  __syncthreads();
  int o4 = tid % 160, th = tid / 160;
  int tb = th * 16;
  float4 acc[16];
  const float4 b4 = *(const float4*)(bias + o4*4);
  #pragma unroll
  for (int i = 0; i < 16; ++i) acc[i] = b4;
  const float* wp = w + o4*4;
  for (int d = 0; d < HD; ++d){
    float4 w4 = *(const float4*)(wp + (long)d*DOUT);
    #pragma unroll
    for (int ii = 0; ii < 4; ++ii){
      float4 h4 = *(const float4*)&hl[d][tb + ii*4];
      float hvv[4] = {h4.x, h4.y, h4.z, h4.w};
      #pragma unroll
      for (int jj = 0; jj < 4; ++jj){
        int i = ii*4 + jj;
        acc[i].x = fmaf(hvv[jj], w4.x, acc[i].x);
        acc[i].y = fmaf(hvv[jj], w4.y, acc[i].y);
        acc[i].z = fmaf(hvv[jj], w4.z, acc[i].z);
        acc[i].w = fmaf(hvv[jj], w4.w, acc[i].w);
      }
    }
  }
  #pragma unroll
  for (int i = 0; i < 16; ++i){
    int t = t0 + tb + i;
    if (t < LSEQ) *(float4*)(out + ((long)(b*LSEQ) + t)*DOUT + o4*4) = acc[i];
  }
}

extern "C" void kernel_launch(void* const* d_in, const int* in_sizes, int n_in,
                              void* d_out, int out_size, void* d_ws, size_t ws_size,
                              hipStream_t stream){
  const float* x     = (const float*)d_in[0];
  const float* pw1_w = (const float*)d_in[1];
  const float* pw1_b = (const float*)d_in[2];
  const float* gn1_g = (const float*)d_in[3];
  const float* gn1_b = (const float*)d_in[4];
  const float* dw_w  = (const float*)d_in[5];
  const float* dw_b  = (const float*)d_in[6];
  const float* gn2_g = (const float*)d_in[7];
  const float* gn2_b = (const float*)d_in[8];
  const float* pw2_w = (const float*)d_in[9];
  const float* pw2_b = (const float*)d_in[10];
  const float* enc_w = (const float*)d_in[11];
  const float* enc_b = (const float*)d_in[12];
  const float* log_dt= (const float*)d_in[13];
  const float* logA  = (const float*)d_in[14];
  const float* Aim   = (const float*)d_in[15];
  const float* Cre   = (const float*)d_in[16];
  const float* Cim   = (const float*)d_in[17];
  const float* Dp    = (const float*)d_in[18];
  const float* owp   = (const float*)d_in[19];
  const float* obp   = (const float*)d_in[20];
  const float* lng   = (const float*)d_in[21];
  const float* lnb   = (const float*)d_in[22];
  const float* dec_w = (const float*)d_in[23];
  const float* dec_b = (const float*)d_in[24];
  float* out = (float*)d_out;

  float* ws   = (float*)d_ws;
  float* u1   = ws;
  float* u2   = u1 + 2097152;
  float* vv   = u2 + 1048576;
  float* hbuf = vv + 1033728;
  float* coef = hbuf + 2097152;
  float* stats= coef + 131072;
  float* ktap = stats + 128;       // NLAY*HD*64 = 32768 floats
  float* ybuf = u1;

  hipMemsetAsync(stats, 0, 128*sizeof(float), stream);
  k_coef<<<NLAY*HD, 64, 0, stream>>>(log_dt, logA, Aim, Cre, Cim, coef, ktap);
  k_pw1<<<BB*64, 256, 0, stream>>>(x, pw1_w, pw1_b, u1, stats);
  k_gnstat<<<1, 64, 0, stream>>>(stats, 0, (float)(CO*TFULL));
  k_glu_silu<<<BB*32, 256, 0, stream>>>(u1, gn1_g, gn1_b, stats, u2);
  k_dconv<<<BB*CO, 256, 0, stream>>>(u2, dw_w, dw_b, vv, stats);
  k_gnstat<<<1, 64, 0, stream>>>(stats, 1, (float)(CO*LSEQ));
  k_pw2enc<<<BB*32, 256, 0, stream>>>(vv, gn2_g, gn2_b, pw2_w, pw2_b, enc_w, enc_b, stats, hbuf);
  for (int l = 0; l < NLAY; ++l){
    k_s4d<<<BB*HD, 512, 0, stream>>>(hbuf, coef, ktap, l, ybuf);
    k_post<<<BB*32, 256, 0, stream>>>(ybuf, hbuf, Dp, owp, obp, lng, lnb, l);
  }
  k_dec<<<BB*64, 320, 0, stream>>>(hbuf, dec_w, dec_b, out);
}

// Round 6
// 688.055 us; speedup vs baseline: 11.3352x; 1.1393x over previous
//
#include <hip/hip_runtime.h>
#include <math.h>

#define BB   16
#define TFULL 4096
#define T2   2048
#define LSEQ 2019
#define HSTR 2048
#define CIN  64
#define CO   32
#define HD   64
#define NST  64
#define NLAY 8
#define DOUT 640
#define EPSF 1e-5f
#define NCH  32
#define CHL  64
#define EROW 66   // padded row stride (entries, 16B each) for E-table

static __device__ __forceinline__ float sigm(float x){ return 1.f/(1.f + __expf(-x)); }
static __device__ __forceinline__ float gelu_(float x){ return 0.5f*x*(1.f + erff(x*0.7071067811865475f)); }

// ---------------- Stage A: pw1 conv + GN1 partial stats ----------------
__global__ void __launch_bounds__(256) k_pw1(const float* __restrict__ x,
                                             const float* __restrict__ w,
                                             const float* __restrict__ bias,
                                             float* __restrict__ u1,
                                             float* __restrict__ stats){
  int blk = blockIdx.x;
  int b  = blk >> 6;
  int t0 = (blk & 63) << 6;
  __shared__ float xs[CIN][64];
  __shared__ float wsm[CO*CIN];
  __shared__ float red[8];
  int tid = threadIdx.x;
  for (int i = tid; i < CIN*64; i += 256){
    int c = i >> 6, t = i & 63;
    xs[c][t] = x[((long)(b*CIN + c))*TFULL + t0 + t];
  }
  for (int i = tid; i < CO*CIN; i += 256) wsm[i] = w[i];
  __syncthreads();
  int t  = tid & 63;
  int o0 = tid >> 6;
  float lsum = 0.f, lsq = 0.f;
  for (int o = o0; o < CO; o += 4){
    float acc = bias[o];
    #pragma unroll
    for (int c = 0; c < CIN; ++c) acc = fmaf(wsm[o*CIN + c], xs[c][t], acc);
    u1[((long)(b*CO + o))*TFULL + t0 + t] = acc;
    lsum += acc; lsq += acc*acc;
  }
  #pragma unroll
  for (int off = 32; off; off >>= 1){ lsum += __shfl_down(lsum, off); lsq += __shfl_down(lsq, off); }
  if ((tid & 63) == 0){ red[tid>>6] = lsum; red[4 + (tid>>6)] = lsq; }
  __syncthreads();
  if (tid == 0){
    atomicAdd(&stats[b],      red[0]+red[1]+red[2]+red[3]);
    atomicAdd(&stats[16 + b], red[4]+red[5]+red[6]+red[7]);
  }
}

__global__ void k_gnstat(float* __restrict__ stats, int which, float cnt){
  int b = threadIdx.x;
  if (b < BB){
    int o = which * 64;
    float m = stats[o + b] / cnt;
    float v = stats[o + 16 + b] / cnt - m*m;
    stats[o + 32 + b] = m;
    stats[o + 48 + b] = rsqrtf(v + EPSF);
  }
}

// ---------------- Stage A3: GN1 apply + GLU(time) + SiLU ----------------
__global__ void __launch_bounds__(256) k_glu_silu(const float* __restrict__ u1,
                                                  const float* __restrict__ g,
                                                  const float* __restrict__ bb,
                                                  const float* __restrict__ stats,
                                                  float* __restrict__ u2){
  int blk = blockIdx.x;
  int b  = blk >> 5;
  int t0 = (blk & 31) << 6;
  float m = stats[32 + b], r = stats[48 + b];
  int tid = threadIdx.x;
  int t = t0 + (tid & 63);
  for (int c = tid >> 6; c < CO; c += 4){
    long base = ((long)(b*CO + c))*TFULL;
    float a  = u1[base + t];
    float bv = u1[base + t + T2];
    float gc = g[c], bc = bb[c];
    a  = (a  - m)*r*gc + bc;
    bv = (bv - m)*r*gc + bc;
    float z = a * sigm(bv);
    z = z * sigm(z);
    u2[((long)(b*CO + c))*T2 + t] = z;
  }
}

// ---------------- Stage B1: depthwise conv (K=32, pad 1) + GN2 partial stats ----------------
__global__ void __launch_bounds__(256) k_dconv(const float* __restrict__ u2,
                                               const float* __restrict__ w,
                                               const float* __restrict__ bias,
                                               float* __restrict__ v,
                                               float* __restrict__ stats){
  int blk = blockIdx.x;
  int b = blk >> 5, c = blk & 31;
  __shared__ float row[T2 + 2];
  __shared__ float red[8];
  int tid = threadIdx.x;
  if (tid == 0){ row[0] = 0.f; row[T2 + 1] = 0.f; }
  const float* src = u2 + ((long)(b*CO + c))*T2;
  for (int i = tid; i < T2; i += 256) row[1 + i] = src[i];
  __syncthreads();
  float wk[32];
  #pragma unroll
  for (int k = 0; k < 32; ++k) wk[k] = w[c*32 + k];
  float bc = bias[c];
  float lsum = 0.f, lsq = 0.f;
  float* dst = v + ((long)(b*CO + c))*LSEQ;
  for (int t = tid; t < LSEQ; t += 256){
    float acc = bc;
    #pragma unroll
    for (int k = 0; k < 32; ++k) acc = fmaf(wk[k], row[t + k], acc);
    dst[t] = acc;
    lsum += acc; lsq += acc*acc;
  }
  #pragma unroll
  for (int off = 32; off; off >>= 1){ lsum += __shfl_down(lsum, off); lsq += __shfl_down(lsq, off); }
  if ((tid & 63) == 0){ red[tid>>6] = lsum; red[4 + (tid>>6)] = lsq; }
  __syncthreads();
  if (tid == 0){
    atomicAdd(&stats[64 + b], red[0]+red[1]+red[2]+red[3]);
    atomicAdd(&stats[80 + b], red[4]+red[5]+red[6]+red[7]);
  }
}

// ---------------- Stage B3: GN2 apply + pw2 + encoder -> h (B,HD,HSTR) ----------------
__global__ void __launch_bounds__(256) k_pw2enc(const float* __restrict__ v,
                                                const float* __restrict__ g2,
                                                const float* __restrict__ b2,
                                                const float* __restrict__ pw2w,
                                                const float* __restrict__ pw2b,
                                                const float* __restrict__ encw,
                                                const float* __restrict__ encb,
                                                const float* __restrict__ stats,
                                                float* __restrict__ h){
  int blk = blockIdx.x;
  int b  = blk >> 5;
  int t0 = (blk & 31) << 6;
  int tcnt = min(64, LSEQ - t0);
  __shared__ float vn[CO][64];
  __shared__ float p2[CO*CO];
  __shared__ float ew[CO*HD];
  __shared__ float u3[4][CO];
  __shared__ float hout[HD][65];
  int tid = threadIdx.x;
  float m = stats[96 + b], r = stats[112 + b];
  for (int i = tid; i < CO*CO; i += 256){
    int o = i & 31, c = i >> 5;
    p2[c*CO + o] = pw2w[o*CO + c];
  }
  for (int i = tid; i < CO*HD; i += 256) ew[i] = encw[i];
  for (int i = tid; i < CO*64; i += 256){
    int c = i >> 6, t = i & 63;
    float val = 0.f;
    if (t < tcnt) val = v[((long)(b*CO + c))*LSEQ + t0 + t];
    vn[c][t] = (val - m)*r*g2[c] + b2[c];
  }
  __syncthreads();
  int wv = tid >> 6, ln = tid & 63;
  for (int i = 0; i < 16; ++i){
    int tt = wv*16 + i;
    if (ln < CO){
      float acc = pw2b[ln];
      #pragma unroll
      for (int c = 0; c < CO; ++c) acc = fmaf(p2[c*CO + ln], vn[c][tt], acc);
      u3[wv][ln] = acc;
    }
    float hacc = encb[ln];
    #pragma unroll
    for (int c = 0; c < CO; ++c) hacc = fmaf(ew[c*HD + ln], u3[wv][c], hacc);
    hout[ln][tt] = hacc;
  }
  __syncthreads();
  for (int i = tid; i < HD*64; i += 256){
    int d = i >> 6, t = i & 63;
    if (t < tcnt) h[((long)(b*HD + d))*HSTR + t0 + t] = hout[d][t];
  }
}

// ---------------- S4D coefficients + K taps for ALL layers ----------------
// ktap[l][h][k] = 2 Re sum_n cd_n w_n^k  (k=0..63) — batch-independent, computed once.
__global__ void k_coef(const float* __restrict__ log_dt, const float* __restrict__ logA,
                       const float* __restrict__ Aim, const float* __restrict__ Cre,
                       const float* __restrict__ Cim, float* __restrict__ coef,
                       float* __restrict__ ktap){
  int blk = blockIdx.x;
  int l = blk >> 6, hh = blk & 63;
  int n = threadIdx.x;
  __shared__ float tk[64][65];
  float dt = expf(log_dt[l*HD + hh]);
  int idx = (l*HD + hh)*NST + n;
  float Ar = -expf(logA[idx]);
  float Ai = Aim[idx];
  float dr = Ar*dt, di = Ai*dt;
  float er = expf(dr);
  float wr = er*cosf(di), wi = er*sinf(di);
  float inv = 1.f/(Ar*Ar + Ai*Ai);
  float xr = wr - 1.f, xi = wi;
  float qr = (xr*Ar + xi*Ai)*inv;
  float qi = (xi*Ar - xr*Ai)*inv;
  float cr = Cre[idx], ci = Cim[idx];
  float cdr = cr*qr - ci*qi;
  float cdi = cr*qi + ci*qr;
  float* cl = coef + l*4*HD*NST;
  int hn = hh*NST + n;
  cl[hn]            = wr;
  cl[HD*NST + hn]   = wi;
  cl[2*HD*NST + hn] = cdr;
  cl[3*HD*NST + hn] = cdi;
  {
    float pr = cdr, pi = cdi;   // cd * w^0
    for (int k = 0; k < 64; ++k){
      tk[n][k] = pr;
      float t2 = pr*wr - pi*wi; pi = pr*wi + pi*wr; pr = t2;
    }
  }
  __syncthreads();
  {
    float s = 0.f;
    for (int m = 0; m < 64; ++m) s += tk[m][n];
    ktap[(l*HD + hh)*64 + n] = 2.f*s;
  }
}

// ---------------- S4D chunk-parallel scan ----------------
// v7: exactly the v6/R5 body (512 threads, unroll-2 pragmas, 88 VGPR proven spill-free),
// with the LDS pad REMOVED: 59,904 B -> two blocks/CU. R4 established the compiler's
// occupancy heuristic at this LDS caps VGPR at 128 (2 blocks x 8 waves = 4 waves/SIMD);
// R5 established this body's true pressure is 88 < 128 -> fits under the cap, no spills.
// 2 resident blocks hide the phase-2 serial scan + barrier drains that left VALUBusy at 53%.
// Spill diagnostic: FETCH_SIZE must stay ~4 MB (if it balloons, revert to the 82,432 pad).
__global__ void __launch_bounds__(512) k_s4d(const float* __restrict__ h,
                                             const float* __restrict__ coef,
                                             const float* __restrict__ ktap,
                                             int layer, float* __restrict__ y){
  int blk = blockIdx.x;
  int b = blk >> 6, hh = blk & 63;
  __shared__ float u_s[2048];
  __shared__ float Eh[32*EROW*4];
  __shared__ float S_s[NCH*128];
  __shared__ float Kpad[128];
  __shared__ float wc[256];        // wr[64] | wi[64] | cdr[64] | cdi[64]
  int tid = threadIdx.x;
  int n = tid & 63, q = tid >> 6;  // lane, wave (0..7)
  const float* cl = coef + layer*4*HD*NST;
  int hn = hh*NST + n;
  float wr  = cl[hn];
  float wi  = cl[HD*NST + hn];
  const float* up = h + ((long)(b*HD + hh))*HSTR;

  // u load: 512 threads x 4 floats
  {
    int base = tid*4;
    if (base + 4 <= LSEQ){
      *(float4*)&u_s[base] = *(const float4*)(up + base);
    } else {
      #pragma unroll
      for (int k = 0; k < 4; ++k){
        int t = base + k;
        u_s[t] = (t < LSEQ) ? up[t] : 0.f;
      }
    }
  }
  if (q == 0){
    wc[n]       = wr;
    wc[64 + n]  = wi;
    wc[128 + n] = cl[2*HD*NST + hn];
    wc[192 + n] = cl[3*HD*NST + hn];
  }
  if (tid < 64) Kpad[tid] = 0.f;
  else if (tid < 128) Kpad[tid] = ktap[(layer*HD + hh)*64 + (tid - 64)];
  __syncthreads();

  // build FULL E-table: Eh[np][k-1] = float4(2cd_{2np}w^k, 2cd_{2np+1}w^k), k=1..64.
  // 512 threads: np=tid>>4 (0..31), par=(tid&1), seg=(tid&15)>>1 -> k in [seg*8+1, seg*8+8]
  {
    int np = tid >> 4, rr = tid & 15;
    int par = rr & 1, seg = rr >> 1;
    int s = np*2 + par;
    float ws = wc[s], wis = wc[64 + s], crs = wc[128 + s], cis = wc[192 + s];
    float ar = ws, ai = wis;
    #pragma unroll
    for (int t2i = 0; t2i < 3; ++t2i){ float t2 = ar*ar - ai*ai; ai = 2.f*ar*ai; ar = t2; }  // w^8
    float pr = 1.f, pi = 0.f;
    for (int k = 0; k < seg; ++k){ float t2 = pr*ar - pi*ai; pi = pr*ai + pi*ar; pr = t2; }   // w^(8seg)
    { float t2 = pr*ws - pi*wis; pi = pr*wis + pi*ws; pr = t2; }                              // w^(8seg+1)
    float* bp = &Eh[(np*EROW + seg*8)*4 + par*2];
    for (int k = 0; k < 8; ++k){
      float2 ev;
      ev.x = 2.f*(crs*pr - cis*pi);
      ev.y = 2.f*(crs*pi + cis*pr);
      *(float2*)bp = ev;
      float t2 = pr*ws - pi*wis; pi = pr*wis + pi*ws; pr = t2;
      bp += 4;
    }
  }

  // phase 1: per-chunk decayed input sums; wave q owns chunks q*4..q*4+3 (float4 Horner)
  int cbase = q*4;
  {
    float vr[4], vi[4];
    #pragma unroll
    for (int c = 0; c < 4; ++c){ vr[c] = 0.f; vi[c] = 0.f; }
    #pragma unroll 2
    for (int j4 = 0; j4 < 64; j4 += 4){
      #pragma unroll
      for (int c = 0; c < 4; ++c){
        float4 uu = *(const float4*)&u_s[(cbase + c)*64 + j4];
        float xr = vr[c], xi = vi[c];
        float a_r = fmaf(wr, xr,  fmaf(-wi, xi,  uu.x));
        float a_i = fmaf(wr, xi,  wi*xr);
        float b_r = fmaf(wr, a_r, fmaf(-wi, a_i, uu.y));
        float b_i = fmaf(wr, a_i, wi*a_r);
        float c_r = fmaf(wr, b_r, fmaf(-wi, b_i, uu.z));
        float c_i = fmaf(wr, b_i, wi*b_r);
        vr[c] = fmaf(wr, c_r, fmaf(-wi, c_i, uu.w));
        vi[c] = fmaf(wr, c_i, wi*c_r);
      }
    }
    #pragma unroll
    for (int c = 0; c < 4; ++c){
      float2 sv = {vr[c], vi[c]};
      *(float2*)&S_s[(cbase + c)*128 + 2*n] = sv;
    }
  }
  __syncthreads();

  // phase 2 (wave 0): chunk-state exclusive scan (in place)
  if (q == 0){
    float ar = wr, ai = wi;
    #pragma unroll
    for (int s = 0; s < 6; ++s){ float t2 = ar*ar - ai*ai; ai = 2.f*ar*ai; ar = t2; }  // w^64
    float sr = 0.f, si = 0.f;
    for (int c = 0; c < NCH; ++c){
      float vr2 = S_s[c*128 + 2*n], vi2 = S_s[c*128 + 2*n + 1];
      float2 sv = {sr, si};
      *(float2*)&S_s[c*128 + 2*n] = sv;
      float nr = fmaf(ar, sr, fmaf(-ai, si, vr2));
      float ni = fmaf(ar, si, fmaf(ai, sr, vi2));
      sr = nr; si = ni;
    }
  }
  __syncthreads();

  // phase 3: state contributions (np-outer; 1 lane-varying e-read feeds 4 broadcast S-reads)
  float acc[4];
  #pragma unroll
  for (int c = 0; c < 4; ++c) acc[c] = 0.f;
  #pragma unroll 2
  for (int np = 0; np < 32; ++np){
    float4 e = *(const float4*)&Eh[(np*EROW + n)*4];
    #pragma unroll
    for (int c = 0; c < 4; ++c){
      float4 s = *(const float4*)&S_s[(cbase + c)*128 + np*4];
      acc[c] = fmaf(e.x,s.x, fmaf(-e.y,s.y, fmaf(e.z,s.z, fmaf(-e.w,s.w, acc[c]))));
    }
  }

  // in-chunk convolution (taps shared across the thread's 4 chunk-outputs) + store
  const float* Kb = &Kpad[64 + n];
  #pragma unroll 2
  for (int j4 = 0; j4 < 64; j4 += 4){
    float k0 = Kb[-j4], k1 = Kb[-j4-1], k2 = Kb[-j4-2], k3 = Kb[-j4-3];
    #pragma unroll
    for (int c = 0; c < 4; ++c){
      float4 u4 = *(const float4*)&u_s[(cbase + c)*64 + j4];
      acc[c] = fmaf(k0,u4.x, fmaf(k1,u4.y, fmaf(k2,u4.z, fmaf(k3,u4.w, acc[c]))));
    }
  }
  float* yo = y + ((long)(b*HD + hh))*HSTR;
  #pragma unroll
  for (int c = 0; c < 4; ++c){
    int t = (cbase + c)*64 + n;
    if (t < LSEQ) yo[t] = acc[c];
  }
}

// ---------------- S4D post: register-tiled GEMM + GLU + residual + LN ----------------
__global__ void __launch_bounds__(256) k_post(const float* __restrict__ y,
                                              float* __restrict__ h,
                                              const float* __restrict__ D,
                                              const float* __restrict__ ow,
                                              const float* __restrict__ ob,
                                              const float* __restrict__ lng,
                                              const float* __restrict__ lnb,
                                              int layer){
  int blk = blockIdx.x;
  int b  = blk >> 5;
  int t0 = (blk & 31) << 6;
  __shared__ float Ws[64*128];     // [c][o]
  __shared__ float Ys[64*68];      // [c][t]; reused as z-buffer
  __shared__ float mstat[64], rstat[64];
  int tid = threadIdx.x;
  const float* owp = ow + layer*2*HD*HD;
  const float* obp = ob + layer*2*HD;
  {
    int o = tid >> 1, cs = (tid & 1)*32;
    const float* wrow = owp + o*HD + cs;
    #pragma unroll
    for (int k = 0; k < 8; ++k){
      float4 w4 = *(const float4*)(wrow + k*4);
      Ws[(cs + k*4 + 0)*128 + o] = w4.x;
      Ws[(cs + k*4 + 1)*128 + o] = w4.y;
      Ws[(cs + k*4 + 2)*128 + o] = w4.z;
      Ws[(cs + k*4 + 3)*128 + o] = w4.w;
    }
  }
  {
    int c = tid >> 2, qq = tid & 3;
    float dl = D[layer*HD + c];
    const float* yrow = y + ((long)(b*HD + c))*HSTR + t0 + qq*16;
    const float* hrow = h + ((long)(b*HD + c))*HSTR + t0 + qq*16;
    #pragma unroll
    for (int k = 0; k < 4; ++k){
      float4 yv = *(const float4*)(yrow + k*4);
      float4 hv = *(const float4*)(hrow + k*4);
      float4 g4;
      g4.x = gelu_(fmaf(hv.x, dl, yv.x));
      g4.y = gelu_(fmaf(hv.y, dl, yv.y));
      g4.z = gelu_(fmaf(hv.z, dl, yv.z));
      g4.w = gelu_(fmaf(hv.w, dl, yv.w));
      *(float4*)&Ys[c*68 + qq*16 + k*4] = g4;
    }
  }
  __syncthreads();
  int og = tid >> 4, tg = tid & 15;
  int o0 = og*4, tt0 = tg*4;
  float accA[4][4], accG[4][4];
  #pragma unroll
  for (int i = 0; i < 4; ++i){
    float ba = obp[o0 + i], bg = obp[64 + o0 + i];
    #pragma unroll
    for (int j = 0; j < 4; ++j){ accA[i][j] = ba; accG[i][j] = bg; }
  }
  for (int c = 0; c < 64; ++c){
    float4 wa = *(const float4*)&Ws[c*128 + o0];
    float4 wg = *(const float4*)&Ws[c*128 + 64 + o0];
    float4 yv = *(const float4*)&Ys[c*68 + tt0];
    float yvv[4] = {yv.x, yv.y, yv.z, yv.w};
    float wav[4] = {wa.x, wa.y, wa.z, wa.w};
    float wgv[4] = {wg.x, wg.y, wg.z, wg.w};
    #pragma unroll
    for (int i = 0; i < 4; ++i){
      #pragma unroll
      for (int j = 0; j < 4; ++j){
        accA[i][j] = fmaf(wav[i], yvv[j], accA[i][j]);
        accG[i][j] = fmaf(wgv[i], yvv[j], accG[i][j]);
      }
    }
  }
  __syncthreads();
  float r[4][4];
  #pragma unroll
  for (int i = 0; i < 4; ++i){
    int c = o0 + i;
    const float* hrow = h + ((long)(b*HD + c))*HSTR + t0 + tt0;
    #pragma unroll
    for (int j = 0; j < 4; ++j){
      int t = t0 + tt0 + j;
      float hold = (t < LSEQ) ? hrow[j] : 0.f;
      float z = accA[i][j] * sigm(accG[i][j]);
      r[i][j] = z + hold;
    }
    float4 rr = {r[i][0], r[i][1], r[i][2], r[i][3]};
    *(float4*)&Ys[c*68 + tt0] = rr;
  }
  __syncthreads();
  if (tid < 64){
    float s1 = 0.f, s2 = 0.f;
    for (int c = 0; c < 64; ++c){
      float v = Ys[c*68 + tid];
      s1 += v; s2 += v*v;
    }
    float m = s1 * (1.f/64.f);
    float var = fmaf(-m, m, s2 * (1.f/64.f));
    mstat[tid] = m;
    rstat[tid] = rsqrtf(var + EPSF);
  }
  __syncthreads();
  #pragma unroll
  for (int i = 0; i < 4; ++i){
    int c = o0 + i;
    float gl = lng[layer*HD + c], bl = lnb[layer*HD + c];
    float* hrow = h + ((long)(b*HD + c))*HSTR + t0 + tt0;
    if (t0 + tt0 + 3 < LSEQ){
      float4 o4v;
      o4v.x = fmaf((r[i][0] - mstat[tt0+0])*rstat[tt0+0], gl, bl);
      o4v.y = fmaf((r[i][1] - mstat[tt0+1])*rstat[tt0+1], gl, bl);
      o4v.z = fmaf((r[i][2] - mstat[tt0+2])*rstat[tt0+2], gl, bl);
      o4v.w = fmaf((r[i][3] - mstat[tt0+3])*rstat[tt0+3], gl, bl);
      *(float4*)hrow = o4v;
    } else {
      #pragma unroll
      for (int j = 0; j < 4; ++j){
        int t = t0 + tt0 + j;
        if (t < LSEQ) hrow[j] = fmaf((r[i][j] - mstat[tt0+j])*rstat[tt0+j], gl, bl);
      }
    }
  }
}

// ---------------- Decoder: register-blocked, weight-reuse GEMM ----------------
__global__ void __launch_bounds__(320) k_dec(const float* __restrict__ h,
                                             const float* __restrict__ w,
                                             const float* __restrict__ bias,
                                             float* __restrict__ out){
  int blk = blockIdx.x;
  int b  = blk >> 6;
  int t0 = (blk & 63) << 5;
  __shared__ float hl[HD][32];
  int tid = threadIdx.x;
  for (int i = tid; i < HD*32; i += 320){
    int d = i >> 5, t = i & 31;
    int tt = t0 + t;
    hl[d][t] = (tt < LSEQ) ? h[((long)(b*HD + d))*HSTR + tt] : 0.f;
  }
  __syncthreads();
  int o4 = tid % 160, th = tid / 160;
  int tb = th * 16;
  float4 acc[16];
  const float4 b4 = *(const float4*)(bias + o4*4);
  #pragma unroll
  for (int i = 0; i < 16; ++i) acc[i] = b4;
  const float* wp = w + o4*4;
  for (int d = 0; d < HD; ++d){
    float4 w4 = *(const float4*)(wp + (long)d*DOUT);
    #pragma unroll
    for (int ii = 0; ii < 4; ++ii){
      float4 h4 = *(const float4*)&hl[d][tb + ii*4];
      float hvv[4] = {h4.x, h4.y, h4.z, h4.w};
      #pragma unroll
      for (int jj = 0; jj < 4; ++jj){
        int i = ii*4 + jj;
        acc[i].x = fmaf(hvv[jj], w4.x, acc[i].x);
        acc[i].y = fmaf(hvv[jj], w4.y, acc[i].y);
        acc[i].z = fmaf(hvv[jj], w4.z, acc[i].z);
        acc[i].w = fmaf(hvv[jj], w4.w, acc[i].w);
      }
    }
  }
  #pragma unroll
  for (int i = 0; i < 16; ++i){
    int t = t0 + tb + i;
    if (t < LSEQ) *(float4*)(out + ((long)(b*LSEQ) + t)*DOUT + o4*4) = acc[i];
  }
}

extern "C" void kernel_launch(void* const* d_in, const int* in_sizes, int n_in,
                              void* d_out, int out_size, void* d_ws, size_t ws_size,
                              hipStream_t stream){
  const float* x     = (const float*)d_in[0];
  const float* pw1_w = (const float*)d_in[1];
  const float* pw1_b = (const float*)d_in[2];
  const float* gn1_g = (const float*)d_in[3];
  const float* gn1_b = (const float*)d_in[4];
  const float* dw_w  = (const float*)d_in[5];
  const float* dw_b  = (const float*)d_in[6];
  const float* gn2_g = (const float*)d_in[7];
  const float* gn2_b = (const float*)d_in[8];
  const float* pw2_w = (const float*)d_in[9];
  const float* pw2_b = (const float*)d_in[10];
  const float* enc_w = (const float*)d_in[11];
  const float* enc_b = (const float*)d_in[12];
  const float* log_dt= (const float*)d_in[13];
  const float* logA  = (const float*)d_in[14];
  const float* Aim   = (const float*)d_in[15];
  const float* Cre   = (const float*)d_in[16];
  const float* Cim   = (const float*)d_in[17];
  const float* Dp    = (const float*)d_in[18];
  const float* owp   = (const float*)d_in[19];
  const float* obp   = (const float*)d_in[20];
  const float* lng   = (const float*)d_in[21];
  const float* lnb   = (const float*)d_in[22];
  const float* dec_w = (const float*)d_in[23];
  const float* dec_b = (const float*)d_in[24];
  float* out = (float*)d_out;

  float* ws   = (float*)d_ws;
  float* u1   = ws;
  float* u2   = u1 + 2097152;
  float* vv   = u2 + 1048576;
  float* hbuf = vv + 1033728;
  float* coef = hbuf + 2097152;
  float* stats= coef + 131072;
  float* ktap = stats + 128;       // NLAY*HD*64 = 32768 floats
  float* ybuf = u1;

  hipMemsetAsync(stats, 0, 128*sizeof(float), stream);
  k_coef<<<NLAY*HD, 64, 0, stream>>>(log_dt, logA, Aim, Cre, Cim, coef, ktap);
  k_pw1<<<BB*64, 256, 0, stream>>>(x, pw1_w, pw1_b, u1, stats);
  k_gnstat<<<1, 64, 0, stream>>>(stats, 0, (float)(CO*TFULL));
  k_glu_silu<<<BB*32, 256, 0, stream>>>(u1, gn1_g, gn1_b, stats, u2);
  k_dconv<<<BB*CO, 256, 0, stream>>>(u2, dw_w, dw_b, vv, stats);
  k_gnstat<<<1, 64, 0, stream>>>(stats, 1, (float)(CO*LSEQ));
  k_pw2enc<<<BB*32, 256, 0, stream>>>(vv, gn2_g, gn2_b, pw2_w, pw2_b, enc_w, enc_b, stats, hbuf);
  for (int l = 0; l < NLAY; ++l){
    k_s4d<<<BB*HD, 512, 0, stream>>>(hbuf, coef, ktap, l, ybuf);
    k_post<<<BB*32, 256, 0, stream>>>(ybuf, hbuf, Dp, owp, obp, lng, lnb, l);
  }
  k_dec<<<BB*64, 320, 0, stream>>>(hbuf, dec_w, dec_b, out);
}

// Round 7
// 681.005 us; speedup vs baseline: 11.4525x; 1.0104x over previous
//
#include <hip/hip_runtime.h>
#include <math.h>

#define BB   16
#define TFULL 4096
#define T2   2048
#define LSEQ 2019
#define HSTR 2048
#define CIN  64
#define CO   32
#define HD   64
#define NST  64
#define NLAY 8
#define DOUT 640
#define EPSF 1e-5f
#define NCH  32
#define CHL  64
#define EROW 66   // padded row stride (entries, 16B each) for E-table

static __device__ __forceinline__ float sigm(float x){ return 1.f/(1.f + __expf(-x)); }
static __device__ __forceinline__ float gelu_(float x){ return 0.5f*x*(1.f + erff(x*0.7071067811865475f)); }

// ---------------- Stage A: pw1 conv + GN1 partial stats ----------------
__global__ void __launch_bounds__(256) k_pw1(const float* __restrict__ x,
                                             const float* __restrict__ w,
                                             const float* __restrict__ bias,
                                             float* __restrict__ u1,
                                             float* __restrict__ stats){
  int blk = blockIdx.x;
  int b  = blk >> 6;
  int t0 = (blk & 63) << 6;
  __shared__ float xs[CIN][64];
  __shared__ float wsm[CO*CIN];
  __shared__ float red[8];
  int tid = threadIdx.x;
  for (int i = tid; i < CIN*64; i += 256){
    int c = i >> 6, t = i & 63;
    xs[c][t] = x[((long)(b*CIN + c))*TFULL + t0 + t];
  }
  for (int i = tid; i < CO*CIN; i += 256) wsm[i] = w[i];
  __syncthreads();
  int t  = tid & 63;
  int o0 = tid >> 6;
  float lsum = 0.f, lsq = 0.f;
  for (int o = o0; o < CO; o += 4){
    float acc = bias[o];
    #pragma unroll
    for (int c = 0; c < CIN; ++c) acc = fmaf(wsm[o*CIN + c], xs[c][t], acc);
    u1[((long)(b*CO + o))*TFULL + t0 + t] = acc;
    lsum += acc; lsq += acc*acc;
  }
  #pragma unroll
  for (int off = 32; off; off >>= 1){ lsum += __shfl_down(lsum, off); lsq += __shfl_down(lsq, off); }
  if ((tid & 63) == 0){ red[tid>>6] = lsum; red[4 + (tid>>6)] = lsq; }
  __syncthreads();
  if (tid == 0){
    atomicAdd(&stats[b],      red[0]+red[1]+red[2]+red[3]);
    atomicAdd(&stats[16 + b], red[4]+red[5]+red[6]+red[7]);
  }
}

__global__ void k_gnstat(float* __restrict__ stats, int which, float cnt){
  int b = threadIdx.x;
  if (b < BB){
    int o = which * 64;
    float m = stats[o + b] / cnt;
    float v = stats[o + 16 + b] / cnt - m*m;
    stats[o + 32 + b] = m;
    stats[o + 48 + b] = rsqrtf(v + EPSF);
  }
}

// ---------------- Stage A3: GN1 apply + GLU(time) + SiLU ----------------
__global__ void __launch_bounds__(256) k_glu_silu(const float* __restrict__ u1,
                                                  const float* __restrict__ g,
                                                  const float* __restrict__ bb,
                                                  const float* __restrict__ stats,
                                                  float* __restrict__ u2){
  int blk = blockIdx.x;
  int b  = blk >> 5;
  int t0 = (blk & 31) << 6;
  float m = stats[32 + b], r = stats[48 + b];
  int tid = threadIdx.x;
  int t = t0 + (tid & 63);
  for (int c = tid >> 6; c < CO; c += 4){
    long base = ((long)(b*CO + c))*TFULL;
    float a  = u1[base + t];
    float bv = u1[base + t + T2];
    float gc = g[c], bc = bb[c];
    a  = (a  - m)*r*gc + bc;
    bv = (bv - m)*r*gc + bc;
    float z = a * sigm(bv);
    z = z * sigm(z);
    u2[((long)(b*CO + c))*T2 + t] = z;
  }
}

// ---------------- Stage B1: depthwise conv (K=32, pad 1) + GN2 partial stats ----------------
__global__ void __launch_bounds__(256) k_dconv(const float* __restrict__ u2,
                                               const float* __restrict__ w,
                                               const float* __restrict__ bias,
                                               float* __restrict__ v,
                                               float* __restrict__ stats){
  int blk = blockIdx.x;
  int b = blk >> 5, c = blk & 31;
  __shared__ float row[T2 + 2];
  __shared__ float red[8];
  int tid = threadIdx.x;
  if (tid == 0){ row[0] = 0.f; row[T2 + 1] = 0.f; }
  const float* src = u2 + ((long)(b*CO + c))*T2;
  for (int i = tid; i < T2; i += 256) row[1 + i] = src[i];
  __syncthreads();
  float wk[32];
  #pragma unroll
  for (int k = 0; k < 32; ++k) wk[k] = w[c*32 + k];
  float bc = bias[c];
  float lsum = 0.f, lsq = 0.f;
  float* dst = v + ((long)(b*CO + c))*LSEQ;
  for (int t = tid; t < LSEQ; t += 256){
    float acc = bc;
    #pragma unroll
    for (int k = 0; k < 32; ++k) acc = fmaf(wk[k], row[t + k], acc);
    dst[t] = acc;
    lsum += acc; lsq += acc*acc;
  }
  #pragma unroll
  for (int off = 32; off; off >>= 1){ lsum += __shfl_down(lsum, off); lsq += __shfl_down(lsq, off); }
  if ((tid & 63) == 0){ red[tid>>6] = lsum; red[4 + (tid>>6)] = lsq; }
  __syncthreads();
  if (tid == 0){
    atomicAdd(&stats[64 + b], red[0]+red[1]+red[2]+red[3]);
    atomicAdd(&stats[80 + b], red[4]+red[5]+red[6]+red[7]);
  }
}

// ---------------- Stage B3: GN2 apply + pw2 + encoder -> h (B,HD,HSTR) ----------------
__global__ void __launch_bounds__(256) k_pw2enc(const float* __restrict__ v,
                                                const float* __restrict__ g2,
                                                const float* __restrict__ b2,
                                                const float* __restrict__ pw2w,
                                                const float* __restrict__ pw2b,
                                                const float* __restrict__ encw,
                                                const float* __restrict__ encb,
                                                const float* __restrict__ stats,
                                                float* __restrict__ h){
  int blk = blockIdx.x;
  int b  = blk >> 5;
  int t0 = (blk & 31) << 6;
  int tcnt = min(64, LSEQ - t0);
  __shared__ float vn[CO][64];
  __shared__ float p2[CO*CO];
  __shared__ float ew[CO*HD];
  __shared__ float u3[4][CO];
  __shared__ float hout[HD][65];
  int tid = threadIdx.x;
  float m = stats[96 + b], r = stats[112 + b];
  for (int i = tid; i < CO*CO; i += 256){
    int o = i & 31, c = i >> 5;
    p2[c*CO + o] = pw2w[o*CO + c];
  }
  for (int i = tid; i < CO*HD; i += 256) ew[i] = encw[i];
  for (int i = tid; i < CO*64; i += 256){
    int c = i >> 6, t = i & 63;
    float val = 0.f;
    if (t < tcnt) val = v[((long)(b*CO + c))*LSEQ + t0 + t];
    vn[c][t] = (val - m)*r*g2[c] + b2[c];
  }
  __syncthreads();
  int wv = tid >> 6, ln = tid & 63;
  for (int i = 0; i < 16; ++i){
    int tt = wv*16 + i;
    if (ln < CO){
      float acc = pw2b[ln];
      #pragma unroll
      for (int c = 0; c < CO; ++c) acc = fmaf(p2[c*CO + ln], vn[c][tt], acc);
      u3[wv][ln] = acc;
    }
    float hacc = encb[ln];
    #pragma unroll
    for (int c = 0; c < CO; ++c) hacc = fmaf(ew[c*HD + ln], u3[wv][c], hacc);
    hout[ln][tt] = hacc;
  }
  __syncthreads();
  for (int i = tid; i < HD*64; i += 256){
    int d = i >> 6, t = i & 63;
    if (t < tcnt) h[((long)(b*HD + d))*HSTR + t0 + t] = hout[d][t];
  }
}

// ---------------- S4D coefficients + K taps for ALL layers ----------------
// ktap[l][h][k] = 2 Re sum_n cd_n w_n^k  (k=0..63) — batch-independent, computed once.
__global__ void k_coef(const float* __restrict__ log_dt, const float* __restrict__ logA,
                       const float* __restrict__ Aim, const float* __restrict__ Cre,
                       const float* __restrict__ Cim, float* __restrict__ coef,
                       float* __restrict__ ktap){
  int blk = blockIdx.x;
  int l = blk >> 6, hh = blk & 63;
  int n = threadIdx.x;
  __shared__ float tk[64][65];
  float dt = expf(log_dt[l*HD + hh]);
  int idx = (l*HD + hh)*NST + n;
  float Ar = -expf(logA[idx]);
  float Ai = Aim[idx];
  float dr = Ar*dt, di = Ai*dt;
  float er = expf(dr);
  float wr = er*cosf(di), wi = er*sinf(di);
  float inv = 1.f/(Ar*Ar + Ai*Ai);
  float xr = wr - 1.f, xi = wi;
  float qr = (xr*Ar + xi*Ai)*inv;
  float qi = (xi*Ar - xr*Ai)*inv;
  float cr = Cre[idx], ci = Cim[idx];
  float cdr = cr*qr - ci*qi;
  float cdi = cr*qi + ci*qr;
  float* cl = coef + l*4*HD*NST;
  int hn = hh*NST + n;
  cl[hn]            = wr;
  cl[HD*NST + hn]   = wi;
  cl[2*HD*NST + hn] = cdr;
  cl[3*HD*NST + hn] = cdi;
  {
    float pr = cdr, pi = cdi;   // cd * w^0
    for (int k = 0; k < 64; ++k){
      tk[n][k] = pr;
      float t2 = pr*wr - pi*wi; pi = pr*wi + pi*wr; pr = t2;
    }
  }
  __syncthreads();
  {
    float s = 0.f;
    for (int m = 0; m < 64; ++m) s += tk[m][n];
    ktap[(l*HD + hh)*64 + n] = 2.f*s;
  }
}

// ---------------- S4D chunk-parallel scan ----------------
// v7 (FROZEN this round — proven 88 VGPR, zero spill, 2 blocks/CU):
// 512 threads, 4 chunks/wave, acc[4], full E-table built once, unroll-2 pragmas.
__global__ void __launch_bounds__(512) k_s4d(const float* __restrict__ h,
                                             const float* __restrict__ coef,
                                             const float* __restrict__ ktap,
                                             int layer, float* __restrict__ y){
  int blk = blockIdx.x;
  int b = blk >> 6, hh = blk & 63;
  __shared__ float u_s[2048];
  __shared__ float Eh[32*EROW*4];
  __shared__ float S_s[NCH*128];
  __shared__ float Kpad[128];
  __shared__ float wc[256];        // wr[64] | wi[64] | cdr[64] | cdi[64]
  int tid = threadIdx.x;
  int n = tid & 63, q = tid >> 6;  // lane, wave (0..7)
  const float* cl = coef + layer*4*HD*NST;
  int hn = hh*NST + n;
  float wr  = cl[hn];
  float wi  = cl[HD*NST + hn];
  const float* up = h + ((long)(b*HD + hh))*HSTR;

  // u load: 512 threads x 4 floats
  {
    int base = tid*4;
    if (base + 4 <= LSEQ){
      *(float4*)&u_s[base] = *(const float4*)(up + base);
    } else {
      #pragma unroll
      for (int k = 0; k < 4; ++k){
        int t = base + k;
        u_s[t] = (t < LSEQ) ? up[t] : 0.f;
      }
    }
  }
  if (q == 0){
    wc[n]       = wr;
    wc[64 + n]  = wi;
    wc[128 + n] = cl[2*HD*NST + hn];
    wc[192 + n] = cl[3*HD*NST + hn];
  }
  if (tid < 64) Kpad[tid] = 0.f;
  else if (tid < 128) Kpad[tid] = ktap[(layer*HD + hh)*64 + (tid - 64)];
  __syncthreads();

  // build FULL E-table: Eh[np][k-1] = float4(2cd_{2np}w^k, 2cd_{2np+1}w^k), k=1..64.
  // 512 threads: np=tid>>4 (0..31), par=(tid&1), seg=(tid&15)>>1 -> k in [seg*8+1, seg*8+8]
  {
    int np = tid >> 4, rr = tid & 15;
    int par = rr & 1, seg = rr >> 1;
    int s = np*2 + par;
    float ws = wc[s], wis = wc[64 + s], crs = wc[128 + s], cis = wc[192 + s];
    float ar = ws, ai = wis;
    #pragma unroll
    for (int t2i = 0; t2i < 3; ++t2i){ float t2 = ar*ar - ai*ai; ai = 2.f*ar*ai; ar = t2; }  // w^8
    float pr = 1.f, pi = 0.f;
    for (int k = 0; k < seg; ++k){ float t2 = pr*ar - pi*ai; pi = pr*ai + pi*ar; pr = t2; }   // w^(8seg)
    { float t2 = pr*ws - pi*wis; pi = pr*wis + pi*ws; pr = t2; }                              // w^(8seg+1)
    float* bp = &Eh[(np*EROW + seg*8)*4 + par*2];
    for (int k = 0; k < 8; ++k){
      float2 ev;
      ev.x = 2.f*(crs*pr - cis*pi);
      ev.y = 2.f*(crs*pi + cis*pr);
      *(float2*)bp = ev;
      float t2 = pr*ws - pi*wis; pi = pr*wis + pi*ws; pr = t2;
      bp += 4;
    }
  }

  // phase 1: per-chunk decayed input sums; wave q owns chunks q*4..q*4+3 (float4 Horner)
  int cbase = q*4;
  {
    float vr[4], vi[4];
    #pragma unroll
    for (int c = 0; c < 4; ++c){ vr[c] = 0.f; vi[c] = 0.f; }
    #pragma unroll 2
    for (int j4 = 0; j4 < 64; j4 += 4){
      #pragma unroll
      for (int c = 0; c < 4; ++c){
        float4 uu = *(const float4*)&u_s[(cbase + c)*64 + j4];
        float xr = vr[c], xi = vi[c];
        float a_r = fmaf(wr, xr,  fmaf(-wi, xi,  uu.x));
        float a_i = fmaf(wr, xi,  wi*xr);
        float b_r = fmaf(wr, a_r, fmaf(-wi, a_i, uu.y));
        float b_i = fmaf(wr, a_i, wi*a_r);
        float c_r = fmaf(wr, b_r, fmaf(-wi, b_i, uu.z));
        float c_i = fmaf(wr, b_i, wi*b_r);
        vr[c] = fmaf(wr, c_r, fmaf(-wi, c_i, uu.w));
        vi[c] = fmaf(wr, c_i, wi*c_r);
      }
    }
    #pragma unroll
    for (int c = 0; c < 4; ++c){
      float2 sv = {vr[c], vi[c]};
      *(float2*)&S_s[(cbase + c)*128 + 2*n] = sv;
    }
  }
  __syncthreads();

  // phase 2 (wave 0): chunk-state exclusive scan (in place)
  if (q == 0){
    float ar = wr, ai = wi;
    #pragma unroll
    for (int s = 0; s < 6; ++s){ float t2 = ar*ar - ai*ai; ai = 2.f*ar*ai; ar = t2; }  // w^64
    float sr = 0.f, si = 0.f;
    for (int c = 0; c < NCH; ++c){
      float vr2 = S_s[c*128 + 2*n], vi2 = S_s[c*128 + 2*n + 1];
      float2 sv = {sr, si};
      *(float2*)&S_s[c*128 + 2*n] = sv;
      float nr = fmaf(ar, sr, fmaf(-ai, si, vr2));
      float ni = fmaf(ar, si, fmaf(ai, sr, vi2));
      sr = nr; si = ni;
    }
  }
  __syncthreads();

  // phase 3: state contributions (np-outer; 1 lane-varying e-read feeds 4 broadcast S-reads)
  float acc[4];
  #pragma unroll
  for (int c = 0; c < 4; ++c) acc[c] = 0.f;
  #pragma unroll 2
  for (int np = 0; np < 32; ++np){
    float4 e = *(const float4*)&Eh[(np*EROW + n)*4];
    #pragma unroll
    for (int c = 0; c < 4; ++c){
      float4 s = *(const float4*)&S_s[(cbase + c)*128 + np*4];
      acc[c] = fmaf(e.x,s.x, fmaf(-e.y,s.y, fmaf(e.z,s.z, fmaf(-e.w,s.w, acc[c]))));
    }
  }

  // in-chunk convolution (taps shared across the thread's 4 chunk-outputs) + store
  const float* Kb = &Kpad[64 + n];
  #pragma unroll 2
  for (int j4 = 0; j4 < 64; j4 += 4){
    float k0 = Kb[-j4], k1 = Kb[-j4-1], k2 = Kb[-j4-2], k3 = Kb[-j4-3];
    #pragma unroll
    for (int c = 0; c < 4; ++c){
      float4 u4 = *(const float4*)&u_s[(cbase + c)*64 + j4];
      acc[c] = fmaf(k0,u4.x, fmaf(k1,u4.y, fmaf(k2,u4.z, fmaf(k3,u4.w, acc[c]))));
    }
  }
  float* yo = y + ((long)(b*HD + hh))*HSTR;
  #pragma unroll
  for (int c = 0; c < 4; ++c){
    int t = (cbase + c)*64 + n;
    if (t < LSEQ) yo[t] = acc[c];
  }
}

// ---------------- S4D post: register-tiled GEMM + GLU + residual + LN ----------------
__global__ void __launch_bounds__(256) k_post(const float* __restrict__ y,
                                              float* __restrict__ h,
                                              const float* __restrict__ D,
                                              const float* __restrict__ ow,
                                              const float* __restrict__ ob,
                                              const float* __restrict__ lng,
                                              const float* __restrict__ lnb,
                                              int layer){
  int blk = blockIdx.x;
  int b  = blk >> 5;
  int t0 = (blk & 31) << 6;
  __shared__ float Ws[64*128];     // [c][o]
  __shared__ float Ys[64*68];      // [c][t]; reused as z-buffer
  __shared__ float mstat[64], rstat[64];
  int tid = threadIdx.x;
  const float* owp = ow + layer*2*HD*HD;
  const float* obp = ob + layer*2*HD;
  {
    int o = tid >> 1, cs = (tid & 1)*32;
    const float* wrow = owp + o*HD + cs;
    #pragma unroll
    for (int k = 0; k < 8; ++k){
      float4 w4 = *(const float4*)(wrow + k*4);
      Ws[(cs + k*4 + 0)*128 + o] = w4.x;
      Ws[(cs + k*4 + 1)*128 + o] = w4.y;
      Ws[(cs + k*4 + 2)*128 + o] = w4.z;
      Ws[(cs + k*4 + 3)*128 + o] = w4.w;
    }
  }
  {
    int c = tid >> 2, qq = tid & 3;
    float dl = D[layer*HD + c];
    const float* yrow = y + ((long)(b*HD + c))*HSTR + t0 + qq*16;
    const float* hrow = h + ((long)(b*HD + c))*HSTR + t0 + qq*16;
    #pragma unroll
    for (int k = 0; k < 4; ++k){
      float4 yv = *(const float4*)(yrow + k*4);
      float4 hv = *(const float4*)(hrow + k*4);
      float4 g4;
      g4.x = gelu_(fmaf(hv.x, dl, yv.x));
      g4.y = gelu_(fmaf(hv.y, dl, yv.y));
      g4.z = gelu_(fmaf(hv.z, dl, yv.z));
      g4.w = gelu_(fmaf(hv.w, dl, yv.w));
      *(float4*)&Ys[c*68 + qq*16 + k*4] = g4;
    }
  }
  __syncthreads();
  int og = tid >> 4, tg = tid & 15;
  int o0 = og*4, tt0 = tg*4;
  float accA[4][4], accG[4][4];
  #pragma unroll
  for (int i = 0; i < 4; ++i){
    float ba = obp[o0 + i], bg = obp[64 + o0 + i];
    #pragma unroll
    for (int j = 0; j < 4; ++j){ accA[i][j] = ba; accG[i][j] = bg; }
  }
  for (int c = 0; c < 64; ++c){
    float4 wa = *(const float4*)&Ws[c*128 + o0];
    float4 wg = *(const float4*)&Ws[c*128 + 64 + o0];
    float4 yv = *(const float4*)&Ys[c*68 + tt0];
    float yvv[4] = {yv.x, yv.y, yv.z, yv.w};
    float wav[4] = {wa.x, wa.y, wa.z, wa.w};
    float wgv[4] = {wg.x, wg.y, wg.z, wg.w};
    #pragma unroll
    for (int i = 0; i < 4; ++i){
      #pragma unroll
      for (int j = 0; j < 4; ++j){
        accA[i][j] = fmaf(wav[i], yvv[j], accA[i][j]);
        accG[i][j] = fmaf(wgv[i], yvv[j], accG[i][j]);
      }
    }
  }
  __syncthreads();
  float r[4][4];
  #pragma unroll
  for (int i = 0; i < 4; ++i){
    int c = o0 + i;
    const float* hrow = h + ((long)(b*HD + c))*HSTR + t0 + tt0;
    #pragma unroll
    for (int j = 0; j < 4; ++j){
      int t = t0 + tt0 + j;
      float hold = (t < LSEQ) ? hrow[j] : 0.f;
      float z = accA[i][j] * sigm(accG[i][j]);
      r[i][j] = z + hold;
    }
    float4 rr = {r[i][0], r[i][1], r[i][2], r[i][3]};
    *(float4*)&Ys[c*68 + tt0] = rr;
  }
  __syncthreads();
  if (tid < 64){
    float s1 = 0.f, s2 = 0.f;
    for (int c = 0; c < 64; ++c){
      float v = Ys[c*68 + tid];
      s1 += v; s2 += v*v;
    }
    float m = s1 * (1.f/64.f);
    float var = fmaf(-m, m, s2 * (1.f/64.f));
    mstat[tid] = m;
    rstat[tid] = rsqrtf(var + EPSF);
  }
  __syncthreads();
  #pragma unroll
  for (int i = 0; i < 4; ++i){
    int c = o0 + i;
    float gl = lng[layer*HD + c], bl = lnb[layer*HD + c];
    float* hrow = h + ((long)(b*HD + c))*HSTR + t0 + tt0;
    if (t0 + tt0 + 3 < LSEQ){
      float4 o4v;
      o4v.x = fmaf((r[i][0] - mstat[tt0+0])*rstat[tt0+0], gl, bl);
      o4v.y = fmaf((r[i][1] - mstat[tt0+1])*rstat[tt0+1], gl, bl);
      o4v.z = fmaf((r[i][2] - mstat[tt0+2])*rstat[tt0+2], gl, bl);
      o4v.w = fmaf((r[i][3] - mstat[tt0+3])*rstat[tt0+3], gl, bl);
      *(float4*)hrow = o4v;
    } else {
      #pragma unroll
      for (int j = 0; j < 4; ++j){
        int t = t0 + tt0 + j;
        if (t < LSEQ) hrow[j] = fmaf((r[i][j] - mstat[tt0+j])*rstat[tt0+j], gl, bl);
      }
    }
  }
}

// ---------------- Decoder: occupancy-focused register-blocked GEMM ----------------
// v2: t-tile 16 (grid 2048 blocks), acc[8] per thread (32 VGPR of acc, was 64).
// R6 counters: 53 us at 21% HBM, VALUBusy 36%, Occupancy 23% -> latency-bound, not BW.
// More resident blocks (~6/CU) + shorter per-thread chains overlap w-loads and stores.
__global__ void __launch_bounds__(320) k_dec(const float* __restrict__ h,
                                             const float* __restrict__ w,
                                             const float* __restrict__ bias,
                                             float* __restrict__ out){
  int blk = blockIdx.x;
  int b  = blk >> 7;
  int t0 = (blk & 127) << 4;
  __shared__ float hl[HD][16];
  int tid = threadIdx.x;
  for (int i = tid; i < HD*16; i += 320){
    int d = i >> 4, t = i & 15;
    int tt = t0 + t;
    hl[d][t] = (tt < LSEQ) ? h[((long)(b*HD + d))*HSTR + tt] : 0.f;
  }
  __syncthreads();
  int o4 = tid % 160, th = tid / 160;   // th in {0,1}
  int tb = th * 8;
  float4 acc[8];
  const float4 b4 = *(const float4*)(bias + o4*4);
  #pragma unroll
  for (int i = 0; i < 8; ++i) acc[i] = b4;
  const float* wp = w + o4*4;
  for (int d = 0; d < HD; ++d){
    float4 w4 = *(const float4*)(wp + (long)d*DOUT);
    #pragma unroll
    for (int ii = 0; ii < 2; ++ii){
      float4 h4 = *(const float4*)&hl[d][tb + ii*4];
      float hvv[4] = {h4.x, h4.y, h4.z, h4.w};
      #pragma unroll
      for (int jj = 0; jj < 4; ++jj){
        int i = ii*4 + jj;
        acc[i].x = fmaf(hvv[jj], w4.x, acc[i].x);
        acc[i].y = fmaf(hvv[jj], w4.y, acc[i].y);
        acc[i].z = fmaf(hvv[jj], w4.z, acc[i].z);
        acc[i].w = fmaf(hvv[jj], w4.w, acc[i].w);
      }
    }
  }
  #pragma unroll
  for (int i = 0; i < 8; ++i){
    int t = t0 + tb + i;
    if (t < LSEQ) *(float4*)(out + ((long)(b*LSEQ) + t)*DOUT + o4*4) = acc[i];
  }
}

extern "C" void kernel_launch(void* const* d_in, const int* in_sizes, int n_in,
                              void* d_out, int out_size, void* d_ws, size_t ws_size,
                              hipStream_t stream){
  const float* x     = (const float*)d_in[0];
  const float* pw1_w = (const float*)d_in[1];
  const float* pw1_b = (const float*)d_in[2];
  const float* gn1_g = (const float*)d_in[3];
  const float* gn1_b = (const float*)d_in[4];
  const float* dw_w  = (const float*)d_in[5];
  const float* dw_b  = (const float*)d_in[6];
  const float* gn2_g = (const float*)d_in[7];
  const float* gn2_b = (const float*)d_in[8];
  const float* pw2_w = (const float*)d_in[9];
  const float* pw2_b = (const float*)d_in[10];
  const float* enc_w = (const float*)d_in[11];
  const float* enc_b = (const float*)d_in[12];
  const float* log_dt= (const float*)d_in[13];
  const float* logA  = (const float*)d_in[14];
  const float* Aim   = (const float*)d_in[15];
  const float* Cre   = (const float*)d_in[16];
  const float* Cim   = (const float*)d_in[17];
  const float* Dp    = (const float*)d_in[18];
  const float* owp   = (const float*)d_in[19];
  const float* obp   = (const float*)d_in[20];
  const float* lng   = (const float*)d_in[21];
  const float* lnb   = (const float*)d_in[22];
  const float* dec_w = (const float*)d_in[23];
  const float* dec_b = (const float*)d_in[24];
  float* out = (float*)d_out;

  float* ws   = (float*)d_ws;
  float* u1   = ws;
  float* u2   = u1 + 2097152;
  float* vv   = u2 + 1048576;
  float* hbuf = vv + 1033728;
  float* coef = hbuf + 2097152;
  float* stats= coef + 131072;
  float* ktap = stats + 128;       // NLAY*HD*64 = 32768 floats
  float* ybuf = u1;

  hipMemsetAsync(stats, 0, 128*sizeof(float), stream);
  k_coef<<<NLAY*HD, 64, 0, stream>>>(log_dt, logA, Aim, Cre, Cim, coef, ktap);
  k_pw1<<<BB*64, 256, 0, stream>>>(x, pw1_w, pw1_b, u1, stats);
  k_gnstat<<<1, 64, 0, stream>>>(stats, 0, (float)(CO*TFULL));
  k_glu_silu<<<BB*32, 256, 0, stream>>>(u1, gn1_g, gn1_b, stats, u2);
  k_dconv<<<BB*CO, 256, 0, stream>>>(u2, dw_w, dw_b, vv, stats);
  k_gnstat<<<1, 64, 0, stream>>>(stats, 1, (float)(CO*LSEQ));
  k_pw2enc<<<BB*32, 256, 0, stream>>>(vv, gn2_g, gn2_b, pw2_w, pw2_b, enc_w, enc_b, stats, hbuf);
  for (int l = 0; l < NLAY; ++l){
    k_s4d<<<BB*HD, 512, 0, stream>>>(hbuf, coef, ktap, l, ybuf);
    k_post<<<BB*32, 256, 0, stream>>>(ybuf, hbuf, Dp, owp, obp, lng, lnb, l);
  }
  k_dec<<<BB*128, 320, 0, stream>>>(hbuf, dec_w, dec_b, out);
}